// Round 13
// baseline (2791.542 us; speedup 1.0000x reference)
//
#include <hip/hip_runtime.h>

#define NN 50000
#define NE 1600000
#define DIM 128
#define NG  512
#define MAXD 192      // bucket capacity; Poisson(lambda=32), overflow probability astronomically small
#define NBIN 8
#define BINW 6250     // NN / NBIN
#define BCAP 210000   // bin capacity; expected 200k, 22-sigma margin

typedef int      vint4   __attribute__((ext_vector_type(4)));
typedef float    vfloat4 __attribute__((ext_vector_type(4)));
typedef float    floatx4 __attribute__((ext_vector_type(4)));
typedef unsigned vuint4  __attribute__((ext_vector_type(4)));
typedef _Float16 half2v  __attribute__((ext_vector_type(2)));
typedef _Float16 half8   __attribute__((ext_vector_type(8)));

__device__ __forceinline__ half8 cvt8(vfloat4 a, vfloat4 b) {
    half8 r;
    r[0] = (_Float16)a.x; r[1] = (_Float16)a.y; r[2] = (_Float16)a.z; r[3] = (_Float16)a.w;
    r[4] = (_Float16)b.x; r[5] = (_Float16)b.y; r[6] = (_Float16)b.z; r[7] = (_Float16)b.w;
    return r;
}

// ---------------- fused init: W->frag cvt | zero cursor+pooled+bcnt ----------------
__global__ void initcvt_kernel(const float* __restrict__ W0, const float* __restrict__ W1,
                               const float* __restrict__ W2, half8* __restrict__ wf,
                               int* __restrict__ cursor, float* __restrict__ pooled,
                               int* __restrict__ bcnt) {
    int b = blockIdx.x;
    if (b < 3) {
        const float* Ws[3] = {W0, W1, W2};
        const float* W = Ws[b];
        half8* outp = wf + (size_t)b * 2048;
        for (int idx = threadIdx.x; idx < 2048; idx += 256) {
            int t = idx >> 9;
            int n = (idx >> 6) & 7;
            int ln = idx & 63;
            int q = ln >> 4, c = ln & 15;
            const float* wp = W + (t * 32 + q * 8) * DIM + n * 16 + c;
            half8 f;
#pragma unroll
            for (int j = 0; j < 8; ++j) f[j] = (_Float16)wp[j * DIM];
            outp[idx] = f;
        }
    } else {
        int k = (b - 3) * 256 + threadIdx.x;
        if (k < NN) cursor[k] = 0;
        else if (k < NN + NG * DIM) pooled[k - NN] = 0.f;
        else if (k < NN + NG * DIM + NBIN) bcnt[k - NN - NG * DIM] = 0;
    }
}

// ---------------- phase 1: bin edges by dst range (8 bins), dense appends ----------
// Wave-ballot aggregation: ~1 atomic per (wave,bin); lanes of a bin write
// consecutive offsets -> full-line stores, no write amplification.
__global__ void bin_kernel(const int* __restrict__ src, const int* __restrict__ dst,
                           int* __restrict__ bcnt, unsigned* __restrict__ bins) {
    int e = blockIdx.x * 256 + threadIdx.x;   // grid covers NE exactly
    int lane = threadIdx.x & 63;
    unsigned long long lt = (lane == 63) ? 0x7FFFFFFFFFFFFFFFULL
                                         : ((1ULL << lane) - 1ULL);
    int d = __builtin_nontemporal_load(dst + e);
    int s = __builtin_nontemporal_load(src + e);
    int myb = (int)(((unsigned)d * 21475u) >> 27);          // d / 6250, exact for d<50000
    unsigned rec = (unsigned)s | ((unsigned)(d - myb * BINW) << 16);
#pragma unroll
    for (int bb = 0; bb < NBIN; ++bb) {
        unsigned long long m = __ballot(myb == bb);
        if (myb == bb) {
            int leader = __ffsll((long long)m) - 1;
            int cnt = __popcll(m);
            int base = 0;
            if (lane == leader) base = atomicAdd(&bcnt[bb], cnt);
            base = __shfl(base, leader);
            int off = base + __popcll(m & lt);
            bins[(size_t)bb * BCAP + off] = rec;
        }
    }
}

// ---------------- phase 2: bin -> buckets; bin = blockIdx%8 pins writers to one XCD ----
// All writers of a node's 384B bucket row run on one XCD; its L2 holds the 2.4 MB
// region, so lines fill fully before writeback (kills the 64B-per-record amplification).
__global__ void scatter2_kernel(const unsigned* __restrict__ bins, const int* __restrict__ bcnt,
                                int* __restrict__ cursor, unsigned short* __restrict__ edges) {
    int b = blockIdx.x & 7;        // XCD round-robin heuristic
    int chunk = blockIdx.x >> 3;   // 0..127
    int n = bcnt[b];
    int i0 = (int)((long long)n * chunk / 128);
    int i1 = (int)((long long)n * (chunk + 1) / 128);
    const unsigned* bp = bins + (size_t)b * BCAP;
    int dbase = b * BINW;
    for (int i = i0 + threadIdx.x; i < i1; i += 256) {
        unsigned rec = bp[i];
        int d = dbase + (int)(rec >> 16);
        int pos = atomicAdd(&cursor[d], 1);
        edges[(size_t)d * MAXD + pos] = (unsigned short)(rec & 0xFFFFu);
    }
}

// ---------------- coeffs from bucket counts ----------------
__global__ void coeff_kernel(const int* __restrict__ cnt, float* __restrict__ dq) {
    int i = blockIdx.x * 256 + threadIdx.x;
    if (i >= NN) return;
    dq[i] = 1.0f / sqrtf((float)(cnt[i] + 1));
}

// ---------------- layer-0 GEMM: reads fp32 x directly, converts in-register ----------
__launch_bounds__(256, 2)
__global__ void gemm0_mfma(const float* __restrict__ x, const half8* __restrict__ wfl,
                           _Float16* __restrict__ hout) {
    __shared__ half8 Wf[2048];   // 32 KB
    int tid = threadIdx.x;
    for (int idx = tid; idx < 2048; idx += 256) Wf[idx] = wfl[idx];
    __syncthreads();
    int wid = tid >> 6, lane = tid & 63;
    int q = lane >> 4, m = lane & 15;
    int r0 = blockIdx.x * 64 + wid * 16;
    int arow = r0 + m;
    if (arow > NN - 1) arow = NN - 1;
    const vfloat4* ap = (const vfloat4*)(x + (size_t)arow * DIM + q * 8);
    half8 a0 = cvt8(ap[0],  ap[1]);
    half8 a1 = cvt8(ap[8],  ap[9]);
    half8 a2 = cvt8(ap[16], ap[17]);
    half8 a3 = cvt8(ap[24], ap[25]);
    floatx4 acc[8];
#pragma unroll
    for (int n = 0; n < 8; ++n) acc[n] = (floatx4){0.f, 0.f, 0.f, 0.f};
#pragma unroll
    for (int n = 0; n < 8; ++n)
        acc[n] = __builtin_amdgcn_mfma_f32_16x16x32_f16(a0, Wf[(0 * 8 + n) * 64 + lane], acc[n], 0, 0, 0);
#pragma unroll
    for (int n = 0; n < 8; ++n)
        acc[n] = __builtin_amdgcn_mfma_f32_16x16x32_f16(a1, Wf[(1 * 8 + n) * 64 + lane], acc[n], 0, 0, 0);
#pragma unroll
    for (int n = 0; n < 8; ++n)
        acc[n] = __builtin_amdgcn_mfma_f32_16x16x32_f16(a2, Wf[(2 * 8 + n) * 64 + lane], acc[n], 0, 0, 0);
#pragma unroll
    for (int n = 0; n < 8; ++n)
        acc[n] = __builtin_amdgcn_mfma_f32_16x16x32_f16(a3, Wf[(3 * 8 + n) * 64 + lane], acc[n], 0, 0, 0);
#pragma unroll
    for (int n = 0; n < 8; ++n) {
#pragma unroll
        for (int r = 0; r < 4; ++r) {
            int row = r0 + q * 4 + r;
            if (row < NN)
                hout[(size_t)row * DIM + n * 16 + m] = (_Float16)acc[n][r];
        }
    }
}

// ---------------- GEMM via MFMA: one 64-row group per block (fp16 input) ----------------
__launch_bounds__(256, 2)
__global__ void gemm_mfma(const _Float16* __restrict__ yin, const half8* __restrict__ wfl,
                          _Float16* __restrict__ hout) {
    __shared__ half8 Wf[2048];   // 32 KB
    int tid = threadIdx.x;
    for (int idx = tid; idx < 2048; idx += 256) Wf[idx] = wfl[idx];
    __syncthreads();
    int wid = tid >> 6, lane = tid & 63;
    int q = lane >> 4, m = lane & 15;
    int r0 = blockIdx.x * 64 + wid * 16;
    int arow = r0 + m;
    if (arow > NN - 1) arow = NN - 1;
    const half8* ap = (const half8*)(yin + (size_t)arow * DIM + q * 8);
    half8 a0 = ap[0], a1 = ap[4], a2 = ap[8], a3 = ap[12];
    floatx4 acc[8];
#pragma unroll
    for (int n = 0; n < 8; ++n) acc[n] = (floatx4){0.f, 0.f, 0.f, 0.f};
#pragma unroll
    for (int n = 0; n < 8; ++n)
        acc[n] = __builtin_amdgcn_mfma_f32_16x16x32_f16(a0, Wf[(0 * 8 + n) * 64 + lane], acc[n], 0, 0, 0);
#pragma unroll
    for (int n = 0; n < 8; ++n)
        acc[n] = __builtin_amdgcn_mfma_f32_16x16x32_f16(a1, Wf[(1 * 8 + n) * 64 + lane], acc[n], 0, 0, 0);
#pragma unroll
    for (int n = 0; n < 8; ++n)
        acc[n] = __builtin_amdgcn_mfma_f32_16x16x32_f16(a2, Wf[(2 * 8 + n) * 64 + lane], acc[n], 0, 0, 0);
#pragma unroll
    for (int n = 0; n < 8; ++n)
        acc[n] = __builtin_amdgcn_mfma_f32_16x16x32_f16(a3, Wf[(3 * 8 + n) * 64 + lane], acc[n], 0, 0, 0);
#pragma unroll
    for (int n = 0; n < 8; ++n) {
#pragma unroll
        for (int r = 0; r < 4; ++r) {
            int row = r0 + q * 4 + r;
            if (row < NN)
                hout[(size_t)row * DIM + n * 16 + m] = (_Float16)acc[n][r];
        }
    }
}

// ---------------- fused conv: 16-deep gather + on-the-fly norm + L2norm/ReLU ----------
__launch_bounds__(256, 8)
__global__ void conv_kernel(const half2v* __restrict__ h2, const float* __restrict__ bias,
                            const int* __restrict__ cnt, const unsigned short* __restrict__ edges,
                            const float* __restrict__ dq, half2v* __restrict__ out,
                            const int* __restrict__ batch, float* __restrict__ pooled,
                            int do_pool) {
    int wid = threadIdx.x >> 6;
    int lane = threadIdx.x & 63;
    int node = blockIdx.x * 4 + wid;
    if (node >= NN) return;
    int deg = cnt[node];
    const unsigned short* ep = edges + (size_t)node * MAXD;   // 384B rows, 16B-aligned
    float ax = 0.f, ay = 0.f;
    int e = 0;
    for (; e + 16 <= deg; e += 16) {
        vuint4 pa = __builtin_nontemporal_load((const vuint4*)(ep + e));
        vuint4 pb = __builtin_nontemporal_load((const vuint4*)(ep + e + 8));
        unsigned s[16];
        s[0] = pa.x & 0xFFFFu;  s[1] = pa.x >> 16;
        s[2] = pa.y & 0xFFFFu;  s[3] = pa.y >> 16;
        s[4] = pa.z & 0xFFFFu;  s[5] = pa.z >> 16;
        s[6] = pa.w & 0xFFFFu;  s[7] = pa.w >> 16;
        s[8] = pb.x & 0xFFFFu;  s[9] = pb.x >> 16;
        s[10] = pb.y & 0xFFFFu; s[11] = pb.y >> 16;
        s[12] = pb.z & 0xFFFFu; s[13] = pb.z >> 16;
        s[14] = pb.w & 0xFFFFu; s[15] = pb.w >> 16;
        float dv[16];
        half2v hv[16];
#pragma unroll
        for (int j = 0; j < 16; ++j) {
            dv[j] = dq[s[j]];
            hv[j] = h2[(size_t)s[j] * 64 + lane];
        }
#pragma unroll
        for (int j = 0; j < 16; ++j) {
            ax += dv[j] * (float)hv[j].x;
            ay += dv[j] * (float)hv[j].y;
        }
    }
    for (; e + 8 <= deg; e += 8) {
        vuint4 pa = __builtin_nontemporal_load((const vuint4*)(ep + e));
        unsigned s[8];
        s[0] = pa.x & 0xFFFFu; s[1] = pa.x >> 16;
        s[2] = pa.y & 0xFFFFu; s[3] = pa.y >> 16;
        s[4] = pa.z & 0xFFFFu; s[5] = pa.z >> 16;
        s[6] = pa.w & 0xFFFFu; s[7] = pa.w >> 16;
        float dv[8];
        half2v hv[8];
#pragma unroll
        for (int j = 0; j < 8; ++j) {
            dv[j] = dq[s[j]];
            hv[j] = h2[(size_t)s[j] * 64 + lane];
        }
#pragma unroll
        for (int j = 0; j < 8; ++j) {
            ax += dv[j] * (float)hv[j].x;
            ay += dv[j] * (float)hv[j].y;
        }
    }
    for (; e < deg; ++e) {
        unsigned s = ep[e];
        float ds = dq[s];
        half2v v = h2[(size_t)s * 64 + lane];
        ax += ds * (float)v.x;
        ay += ds * (float)v.y;
    }
    float dqd = dq[node];
    float sn = dqd * dqd;      // selfn = 1/deg = dq^2
    half2v hvn = h2[(size_t)node * 64 + lane];
    ax = ax * dqd + sn * (float)hvn.x + bias[2 * lane];
    ay = ay * dqd + sn * (float)hvn.y + bias[2 * lane + 1];
    float ss = ax * ax + ay * ay;
#pragma unroll
    for (int off = 32; off; off >>= 1) ss += __shfl_xor(ss, off);
    float inv = 1.0f / fmaxf(sqrtf(ss), 1e-12f);
    float ox = fmaxf(ax * inv, 0.f);
    float oy = fmaxf(ay * inv, 0.f);
    if (!do_pool) {
        half2v o;
        o.x = (_Float16)ox;
        o.y = (_Float16)oy;
        out[(size_t)node * 64 + lane] = o;   // cached: y stays L2-hot for next GEMM
    } else {
        int g = batch[node];
        atomicAdd(&pooled[g * DIM + 2 * lane], ox);
        atomicAdd(&pooled[g * DIM + 2 * lane + 1], oy);
    }
}

// ---------------- head: z = relu(pooled@W1+b1); logits = z@W2+b2 ----------------
__launch_bounds__(128)
__global__ void head_kernel(const float* __restrict__ pooled, const float* __restrict__ w1,
                            const float* __restrict__ b1, const float* __restrict__ w2,
                            const float* __restrict__ b2, float* __restrict__ out) {
    __shared__ float sp[DIM];
    __shared__ float red[4];
    int g = blockIdx.x;
    int k = threadIdx.x;
    sp[k] = pooled[g * DIM + k];
    __syncthreads();
    float acc = b1[k];
#pragma unroll 8
    for (int j = 0; j < DIM; ++j) acc += sp[j] * w1[j * DIM + k];
    float z = fmaxf(acc, 0.f);
    float p0 = z * w2[k * 2 + 0];
    float p1 = z * w2[k * 2 + 1];
#pragma unroll
    for (int off = 32; off; off >>= 1) {
        p0 += __shfl_xor(p0, off);
        p1 += __shfl_xor(p1, off);
    }
    if ((k & 63) == 0) {
        red[(k >> 6) * 2 + 0] = p0;
        red[(k >> 6) * 2 + 1] = p1;
    }
    __syncthreads();
    if (k == 0) {
        out[g * 2 + 0] = red[0] + red[2] + b2[0];
        out[g * 2 + 1] = red[1] + red[3] + b2[1];
    }
}

extern "C" void kernel_launch(void* const* d_in, const int* in_sizes, int n_in,
                              void* d_out, int out_size, void* d_ws, size_t ws_size,
                              hipStream_t stream) {
    const float* x    = (const float*)d_in[0];
    const int* eidx   = (const int*)d_in[1];
    const int* batch  = (const int*)d_in[2];
    const float* W0   = (const float*)d_in[3];
    const float* b0   = (const float*)d_in[4];
    const float* W1   = (const float*)d_in[5];
    const float* b1   = (const float*)d_in[6];
    const float* W2   = (const float*)d_in[7];
    const float* b2   = (const float*)d_in[8];
    const float* l1w  = (const float*)d_in[9];
    const float* l1b  = (const float*)d_in[10];
    const float* l2w  = (const float*)d_in[11];
    const float* l2b  = (const float*)d_in[12];
    float* out = (float*)d_out;

    char* w = (char*)d_ws;
    float* dq     = (float*)w; w += (size_t)NN * 4;
    int*   cursor = (int*)w;   w += (size_t)NN * 4;
    int*   bcnt   = (int*)w;   w += 64 * 4;
    unsigned* bins = (unsigned*)w; w += (size_t)NBIN * BCAP * 4;             // 6.7 MB
    unsigned short* edges = (unsigned short*)w; w += (size_t)NN * MAXD * 2;  // 19.2 MB
    half8* wf     = (half8*)w; w += (size_t)3 * 2048 * 16;
    _Float16* bufh = (_Float16*)w; w += (size_t)NN * DIM * 2;   // h (gemm out, gathered)
    _Float16* bufy = (_Float16*)w; w += (size_t)NN * DIM * 2;   // y (conv out)
    float* pooled = (float*)w; w += (size_t)NG * DIM * 4;

    const int* src = eidx;
    const int* dst = eidx + NE;

    initcvt_kernel<<<3 + (NN + NG * DIM + NBIN + 255) / 256, 256, 0, stream>>>(
        W0, W1, W2, wf, cursor, pooled, bcnt);
    bin_kernel<<<NE / 256, 256, 0, stream>>>(src, dst, bcnt, bins);
    scatter2_kernel<<<1024, 256, 0, stream>>>(bins, bcnt, cursor, edges);
    coeff_kernel<<<(NN + 255) / 256, 256, 0, stream>>>(cursor, dq);

    const int CG = (NN + 3) / 4;        // 12500 blocks, one wave per node
    const int GG = (NN + 63) / 64;      // 782 blocks, one 64-row group per block

    gemm0_mfma<<<GG, 256, 0, stream>>>(x, wf, bufh);
    conv_kernel<<<CG, 256, 0, stream>>>((const half2v*)bufh, b0, cursor, edges, dq,
                                        (half2v*)bufy, batch, pooled, 0);
    gemm_mfma<<<GG, 256, 0, stream>>>(bufy, wf + 2048, bufh);
    conv_kernel<<<CG, 256, 0, stream>>>((const half2v*)bufh, b1, cursor, edges, dq,
                                        (half2v*)bufy, batch, pooled, 0);
    gemm_mfma<<<GG, 256, 0, stream>>>(bufy, wf + 4096, bufh);
    conv_kernel<<<CG, 256, 0, stream>>>((const half2v*)bufh, b2, cursor, edges, dq,
                                        (half2v*)bufy, batch, pooled, 1);
    head_kernel<<<NG, 128, 0, stream>>>(pooled, l1w, l1b, l2w, l2b, out);
}

// Round 14
// 572.459 us; speedup vs baseline: 4.8764x; 4.8764x over previous
//
#include <hip/hip_runtime.h>

#define NN 50000
#define NE 1600000
#define DIM 128
#define NG  512
#define NBLK 49        // ceil(NN/1024)

typedef int      vint4   __attribute__((ext_vector_type(4)));
typedef float    vfloat4 __attribute__((ext_vector_type(4)));
typedef float    floatx4 __attribute__((ext_vector_type(4)));
typedef unsigned vuint4  __attribute__((ext_vector_type(4)));
typedef _Float16 half2v  __attribute__((ext_vector_type(2)));
typedef _Float16 half8   __attribute__((ext_vector_type(8)));

__device__ __forceinline__ half8 cvt8(vfloat4 a, vfloat4 b) {
    half8 r;
    r[0] = (_Float16)a.x; r[1] = (_Float16)a.y; r[2] = (_Float16)a.z; r[3] = (_Float16)a.w;
    r[4] = (_Float16)b.x; r[5] = (_Float16)b.y; r[6] = (_Float16)b.z; r[7] = (_Float16)b.w;
    return r;
}

// ---------------- fused init: W->frag cvt | zero cnt+pooled ----------------
__global__ void initcvt_kernel(const float* __restrict__ W0, const float* __restrict__ W1,
                               const float* __restrict__ W2, half8* __restrict__ wf,
                               int* __restrict__ cnt, float* __restrict__ pooled) {
    int b = blockIdx.x;
    if (b < 3) {
        const float* Ws[3] = {W0, W1, W2};
        const float* W = Ws[b];
        half8* outp = wf + (size_t)b * 2048;
        for (int idx = threadIdx.x; idx < 2048; idx += 256) {
            int t = idx >> 9;
            int n = (idx >> 6) & 7;
            int ln = idx & 63;
            int q = ln >> 4, c = ln & 15;
            const float* wp = W + (t * 32 + q * 8) * DIM + n * 16 + c;
            half8 f;
#pragma unroll
            for (int j = 0; j < 8; ++j) f[j] = (_Float16)wp[j * DIM];
            outp[idx] = f;
        }
    } else {
        int k = (b - 3) * 256 + threadIdx.x;
        if (k < NN) cnt[k] = 0;
        else if (k < NN + NG * DIM) pooled[k - NN] = 0.f;
    }
}

// ---------------- count: 4 edges/thread, 50000 counters (low contention) ----------------
__global__ void count_kernel(const int* __restrict__ dst, int* __restrict__ cnt) {
    int e0 = (blockIdx.x * 256 + threadIdx.x) * 4;   // grid covers NE exactly
    vint4 d4 = __builtin_nontemporal_load((const vint4*)(dst + e0));
    atomicAdd(&cnt[d4.x], 1);
    atomicAdd(&cnt[d4.y], 1);
    atomicAdd(&cnt[d4.z], 1);
    atomicAdd(&cnt[d4.w], 1);
}

// ---------------- scan phase 1: per-block local scan + dq coeff ----------------
__global__ void scan1_kernel(const int* __restrict__ cnt, int* __restrict__ lexcl,
                             int* __restrict__ bsum, float* __restrict__ dq) {
    __shared__ int sd[1024];
    int t = threadIdx.x;
    int i = blockIdx.x * 1024 + t;
    int v = (i < NN) ? cnt[i] : 0;
    sd[t] = v;
    __syncthreads();
    for (int off = 1; off < 1024; off <<= 1) {
        int add = (t >= off) ? sd[t - off] : 0;
        __syncthreads();
        sd[t] += add;
        __syncthreads();
    }
    int incl = sd[t];
    if (i < NN) {
        lexcl[i] = incl - v;
        dq[i] = 1.0f / sqrtf((float)(v + 1));
    }
    if (t == 1023) bsum[blockIdx.x] = incl;
}

// ---------------- scan phase 2+3 merged: block offset via wave-reduce, write rowp ----
__global__ void scan23_kernel(const int* __restrict__ lexcl, const int* __restrict__ bsum,
                              int* __restrict__ rowp, int* __restrict__ cursor) {
    __shared__ int s_off;
    int t = threadIdx.x;
    if (t < 64) {
        int v = (t < NBLK) ? bsum[t] : 0;
        int pre = (t < (int)blockIdx.x) ? v : 0;
        int all = v;
#pragma unroll
        for (int off = 32; off; off >>= 1) {
            pre += __shfl_xor(pre, off);
            all += __shfl_xor(all, off);
        }
        if (t == 0) {
            s_off = pre;
            if (blockIdx.x == 0) rowp[NN] = all;   // == NE
        }
    }
    __syncthreads();
    int i = blockIdx.x * 1024 + t;
    if (i < NN) {
        int v = lexcl[i] + s_off;
        rowp[i] = v;
        cursor[i] = v;
    }
}

// ---------------- scatter: 2B records into 3.2 MB CSR, cached stores ----------------
// Small write region -> ~4 records per 64B line per XCD -> ~4x write amp (vs 32x
// with the 19.2 MB bucket layout). Cursor atomics: 50000 addresses, 32 ops each.
__global__ void scatter_kernel(const int* __restrict__ src, const int* __restrict__ dst,
                               int* __restrict__ cursor, unsigned short* __restrict__ edges) {
    int e0 = (blockIdx.x * 256 + threadIdx.x) * 4;   // grid covers NE exactly
    vint4 d4 = __builtin_nontemporal_load((const vint4*)(dst + e0));
    vint4 s4 = __builtin_nontemporal_load((const vint4*)(src + e0));
    int p0 = atomicAdd(&cursor[d4.x], 1);
    edges[p0] = (unsigned short)s4.x;
    int p1 = atomicAdd(&cursor[d4.y], 1);
    edges[p1] = (unsigned short)s4.y;
    int p2 = atomicAdd(&cursor[d4.z], 1);
    edges[p2] = (unsigned short)s4.z;
    int p3 = atomicAdd(&cursor[d4.w], 1);
    edges[p3] = (unsigned short)s4.w;
}

// ---------------- layer-0 GEMM: reads fp32 x directly, converts in-register ----------
__launch_bounds__(256, 2)
__global__ void gemm0_mfma(const float* __restrict__ x, const half8* __restrict__ wfl,
                           _Float16* __restrict__ hout) {
    __shared__ half8 Wf[2048];   // 32 KB
    int tid = threadIdx.x;
    for (int idx = tid; idx < 2048; idx += 256) Wf[idx] = wfl[idx];
    __syncthreads();
    int wid = tid >> 6, lane = tid & 63;
    int q = lane >> 4, m = lane & 15;
    int r0 = blockIdx.x * 64 + wid * 16;
    int arow = r0 + m;
    if (arow > NN - 1) arow = NN - 1;
    const vfloat4* ap = (const vfloat4*)(x + (size_t)arow * DIM + q * 8);
    half8 a0 = cvt8(ap[0],  ap[1]);
    half8 a1 = cvt8(ap[8],  ap[9]);
    half8 a2 = cvt8(ap[16], ap[17]);
    half8 a3 = cvt8(ap[24], ap[25]);
    floatx4 acc[8];
#pragma unroll
    for (int n = 0; n < 8; ++n) acc[n] = (floatx4){0.f, 0.f, 0.f, 0.f};
#pragma unroll
    for (int n = 0; n < 8; ++n)
        acc[n] = __builtin_amdgcn_mfma_f32_16x16x32_f16(a0, Wf[(0 * 8 + n) * 64 + lane], acc[n], 0, 0, 0);
#pragma unroll
    for (int n = 0; n < 8; ++n)
        acc[n] = __builtin_amdgcn_mfma_f32_16x16x32_f16(a1, Wf[(1 * 8 + n) * 64 + lane], acc[n], 0, 0, 0);
#pragma unroll
    for (int n = 0; n < 8; ++n)
        acc[n] = __builtin_amdgcn_mfma_f32_16x16x32_f16(a2, Wf[(2 * 8 + n) * 64 + lane], acc[n], 0, 0, 0);
#pragma unroll
    for (int n = 0; n < 8; ++n)
        acc[n] = __builtin_amdgcn_mfma_f32_16x16x32_f16(a3, Wf[(3 * 8 + n) * 64 + lane], acc[n], 0, 0, 0);
#pragma unroll
    for (int n = 0; n < 8; ++n) {
#pragma unroll
        for (int r = 0; r < 4; ++r) {
            int row = r0 + q * 4 + r;
            if (row < NN)
                hout[(size_t)row * DIM + n * 16 + m] = (_Float16)acc[n][r];
        }
    }
}

// ---------------- GEMM via MFMA: one 64-row group per block (fp16 input) ----------------
__launch_bounds__(256, 2)
__global__ void gemm_mfma(const _Float16* __restrict__ yin, const half8* __restrict__ wfl,
                          _Float16* __restrict__ hout) {
    __shared__ half8 Wf[2048];   // 32 KB
    int tid = threadIdx.x;
    for (int idx = tid; idx < 2048; idx += 256) Wf[idx] = wfl[idx];
    __syncthreads();
    int wid = tid >> 6, lane = tid & 63;
    int q = lane >> 4, m = lane & 15;
    int r0 = blockIdx.x * 64 + wid * 16;
    int arow = r0 + m;
    if (arow > NN - 1) arow = NN - 1;
    const half8* ap = (const half8*)(yin + (size_t)arow * DIM + q * 8);
    half8 a0 = ap[0], a1 = ap[4], a2 = ap[8], a3 = ap[12];
    floatx4 acc[8];
#pragma unroll
    for (int n = 0; n < 8; ++n) acc[n] = (floatx4){0.f, 0.f, 0.f, 0.f};
#pragma unroll
    for (int n = 0; n < 8; ++n)
        acc[n] = __builtin_amdgcn_mfma_f32_16x16x32_f16(a0, Wf[(0 * 8 + n) * 64 + lane], acc[n], 0, 0, 0);
#pragma unroll
    for (int n = 0; n < 8; ++n)
        acc[n] = __builtin_amdgcn_mfma_f32_16x16x32_f16(a1, Wf[(1 * 8 + n) * 64 + lane], acc[n], 0, 0, 0);
#pragma unroll
    for (int n = 0; n < 8; ++n)
        acc[n] = __builtin_amdgcn_mfma_f32_16x16x32_f16(a2, Wf[(2 * 8 + n) * 64 + lane], acc[n], 0, 0, 0);
#pragma unroll
    for (int n = 0; n < 8; ++n)
        acc[n] = __builtin_amdgcn_mfma_f32_16x16x32_f16(a3, Wf[(3 * 8 + n) * 64 + lane], acc[n], 0, 0, 0);
#pragma unroll
    for (int n = 0; n < 8; ++n) {
#pragma unroll
        for (int r = 0; r < 4; ++r) {
            int row = r0 + q * 4 + r;
            if (row < NN)
                hout[(size_t)row * DIM + n * 16 + m] = (_Float16)acc[n][r];
        }
    }
}

// ---------------- fused conv: CSR 16-deep gather + on-the-fly norm + L2norm/ReLU ------
__launch_bounds__(256, 8)
__global__ void conv_kernel(const half2v* __restrict__ h2, const float* __restrict__ bias,
                            const int* __restrict__ rowp, const unsigned short* __restrict__ edges,
                            const float* __restrict__ dq, half2v* __restrict__ out,
                            const int* __restrict__ batch, float* __restrict__ pooled,
                            int do_pool) {
    int wid = threadIdx.x >> 6;
    int lane = threadIdx.x & 63;
    int node = blockIdx.x * 4 + wid;
    if (node >= NN) return;
    int beg = rowp[node], end = rowp[node + 1];
    float ax = 0.f, ay = 0.f;
    int e = beg;
    // scalar head until 16B-aligned (e % 8 == 0)
    for (; e < end && (e & 7); ++e) {
        unsigned s = edges[e];
        float ds = dq[s];
        half2v v = h2[(size_t)s * 64 + lane];
        ax += ds * (float)v.x;
        ay += ds * (float)v.y;
    }
    for (; e + 16 <= end; e += 16) {
        vuint4 pa = __builtin_nontemporal_load((const vuint4*)(edges + e));
        vuint4 pb = __builtin_nontemporal_load((const vuint4*)(edges + e + 8));
        unsigned s[16];
        s[0] = pa.x & 0xFFFFu;  s[1] = pa.x >> 16;
        s[2] = pa.y & 0xFFFFu;  s[3] = pa.y >> 16;
        s[4] = pa.z & 0xFFFFu;  s[5] = pa.z >> 16;
        s[6] = pa.w & 0xFFFFu;  s[7] = pa.w >> 16;
        s[8] = pb.x & 0xFFFFu;  s[9] = pb.x >> 16;
        s[10] = pb.y & 0xFFFFu; s[11] = pb.y >> 16;
        s[12] = pb.z & 0xFFFFu; s[13] = pb.z >> 16;
        s[14] = pb.w & 0xFFFFu; s[15] = pb.w >> 16;
        float dv[16];
        half2v hv[16];
#pragma unroll
        for (int j = 0; j < 16; ++j) {
            dv[j] = dq[s[j]];
            hv[j] = h2[(size_t)s[j] * 64 + lane];
        }
#pragma unroll
        for (int j = 0; j < 16; ++j) {
            ax += dv[j] * (float)hv[j].x;
            ay += dv[j] * (float)hv[j].y;
        }
    }
    for (; e + 8 <= end; e += 8) {
        vuint4 pa = __builtin_nontemporal_load((const vuint4*)(edges + e));
        unsigned s[8];
        s[0] = pa.x & 0xFFFFu; s[1] = pa.x >> 16;
        s[2] = pa.y & 0xFFFFu; s[3] = pa.y >> 16;
        s[4] = pa.z & 0xFFFFu; s[5] = pa.z >> 16;
        s[6] = pa.w & 0xFFFFu; s[7] = pa.w >> 16;
        float dv[8];
        half2v hv[8];
#pragma unroll
        for (int j = 0; j < 8; ++j) {
            dv[j] = dq[s[j]];
            hv[j] = h2[(size_t)s[j] * 64 + lane];
        }
#pragma unroll
        for (int j = 0; j < 8; ++j) {
            ax += dv[j] * (float)hv[j].x;
            ay += dv[j] * (float)hv[j].y;
        }
    }
    for (; e < end; ++e) {
        unsigned s = edges[e];
        float ds = dq[s];
        half2v v = h2[(size_t)s * 64 + lane];
        ax += ds * (float)v.x;
        ay += ds * (float)v.y;
    }
    float dqd = dq[node];
    float sn = dqd * dqd;      // selfn = 1/deg = dq^2
    half2v hvn = h2[(size_t)node * 64 + lane];
    ax = ax * dqd + sn * (float)hvn.x + bias[2 * lane];
    ay = ay * dqd + sn * (float)hvn.y + bias[2 * lane + 1];
    float ss = ax * ax + ay * ay;
#pragma unroll
    for (int off = 32; off; off >>= 1) ss += __shfl_xor(ss, off);
    float inv = 1.0f / fmaxf(sqrtf(ss), 1e-12f);
    float ox = fmaxf(ax * inv, 0.f);
    float oy = fmaxf(ay * inv, 0.f);
    if (!do_pool) {
        half2v o;
        o.x = (_Float16)ox;
        o.y = (_Float16)oy;
        out[(size_t)node * 64 + lane] = o;   // cached: y stays L2-hot for next GEMM
    } else {
        int g = batch[node];
        atomicAdd(&pooled[g * DIM + 2 * lane], ox);
        atomicAdd(&pooled[g * DIM + 2 * lane + 1], oy);
    }
}

// ---------------- head: z = relu(pooled@W1+b1); logits = z@W2+b2 ----------------
__launch_bounds__(128)
__global__ void head_kernel(const float* __restrict__ pooled, const float* __restrict__ w1,
                            const float* __restrict__ b1, const float* __restrict__ w2,
                            const float* __restrict__ b2, float* __restrict__ out) {
    __shared__ float sp[DIM];
    __shared__ float red[4];
    int g = blockIdx.x;
    int k = threadIdx.x;
    sp[k] = pooled[g * DIM + k];
    __syncthreads();
    float acc = b1[k];
#pragma unroll 8
    for (int j = 0; j < DIM; ++j) acc += sp[j] * w1[j * DIM + k];
    float z = fmaxf(acc, 0.f);
    float p0 = z * w2[k * 2 + 0];
    float p1 = z * w2[k * 2 + 1];
#pragma unroll
    for (int off = 32; off; off >>= 1) {
        p0 += __shfl_xor(p0, off);
        p1 += __shfl_xor(p1, off);
    }
    if ((k & 63) == 0) {
        red[(k >> 6) * 2 + 0] = p0;
        red[(k >> 6) * 2 + 1] = p1;
    }
    __syncthreads();
    if (k == 0) {
        out[g * 2 + 0] = red[0] + red[2] + b2[0];
        out[g * 2 + 1] = red[1] + red[3] + b2[1];
    }
}

extern "C" void kernel_launch(void* const* d_in, const int* in_sizes, int n_in,
                              void* d_out, int out_size, void* d_ws, size_t ws_size,
                              hipStream_t stream) {
    const float* x    = (const float*)d_in[0];
    const int* eidx   = (const int*)d_in[1];
    const int* batch  = (const int*)d_in[2];
    const float* W0   = (const float*)d_in[3];
    const float* b0   = (const float*)d_in[4];
    const float* W1   = (const float*)d_in[5];
    const float* b1   = (const float*)d_in[6];
    const float* W2   = (const float*)d_in[7];
    const float* b2   = (const float*)d_in[8];
    const float* l1w  = (const float*)d_in[9];
    const float* l1b  = (const float*)d_in[10];
    const float* l2w  = (const float*)d_in[11];
    const float* l2b  = (const float*)d_in[12];
    float* out = (float*)d_out;

    char* w = (char*)d_ws;
    float* dq     = (float*)w; w += (size_t)NN * 4;
    int*   cnt    = (int*)w;   w += (size_t)NN * 4;
    int*   rowp   = (int*)w;   w += (size_t)(NN + 8) * 4;
    int*   cursor = (int*)w;   w += (size_t)NN * 4;
    int*   lexcl  = (int*)w;   w += (size_t)NN * 4;
    int*   bsum   = (int*)w;   w += 1024 * 4;
    unsigned short* edges = (unsigned short*)w; w += (size_t)NE * 2;   // 3.2 MB CSR
    half8* wf     = (half8*)w; w += (size_t)3 * 2048 * 16;
    _Float16* bufh = (_Float16*)w; w += (size_t)NN * DIM * 2;   // h (gemm out, gathered)
    _Float16* bufy = (_Float16*)w; w += (size_t)NN * DIM * 2;   // y (conv out)
    float* pooled = (float*)w; w += (size_t)NG * DIM * 4;

    const int* src = eidx;
    const int* dst = eidx + NE;

    initcvt_kernel<<<3 + (NN + NG * DIM + 255) / 256, 256, 0, stream>>>(W0, W1, W2, wf,
                                                                        cnt, pooled);
    count_kernel<<<NE / 4 / 256, 256, 0, stream>>>(dst, cnt);
    scan1_kernel<<<NBLK, 1024, 0, stream>>>(cnt, lexcl, bsum, dq);
    scan23_kernel<<<NBLK, 1024, 0, stream>>>(lexcl, bsum, rowp, cursor);
    scatter_kernel<<<NE / 4 / 256, 256, 0, stream>>>(src, dst, cursor, edges);

    const int CG = (NN + 3) / 4;        // 12500 blocks, one wave per node
    const int GG = (NN + 63) / 64;      // 782 blocks, one 64-row group per block

    gemm0_mfma<<<GG, 256, 0, stream>>>(x, wf, bufh);
    conv_kernel<<<CG, 256, 0, stream>>>((const half2v*)bufh, b0, rowp, edges, dq,
                                        (half2v*)bufy, batch, pooled, 0);
    gemm_mfma<<<GG, 256, 0, stream>>>(bufy, wf + 2048, bufh);
    conv_kernel<<<CG, 256, 0, stream>>>((const half2v*)bufh, b1, rowp, edges, dq,
                                        (half2v*)bufy, batch, pooled, 0);
    gemm_mfma<<<GG, 256, 0, stream>>>(bufy, wf + 4096, bufh);
    conv_kernel<<<CG, 256, 0, stream>>>((const half2v*)bufh, b2, rowp, edges, dq,
                                        (half2v*)bufy, batch, pooled, 1);
    head_kernel<<<NG, 128, 0, stream>>>(pooled, l1w, l1b, l2w, l2b, out);
}

// Round 15
// 520.748 us; speedup vs baseline: 5.3606x; 1.0993x over previous
//
#include <hip/hip_runtime.h>

#define NN 50000
#define NE 1600000
#define DIM 128
#define NG  512
#define NCH 391        // ceil(NE/4096) edge chunks
#define CHSZ 4096
#define NBINS 196      // bin = dst >> 8 (dst < 50000 -> 0..195)
#define BINCAP 16384   // padded CSR slots per bin (expected ~10000)

typedef int      vint4   __attribute__((ext_vector_type(4)));
typedef float    vfloat4 __attribute__((ext_vector_type(4)));
typedef float    floatx4 __attribute__((ext_vector_type(4)));
typedef unsigned vuint4  __attribute__((ext_vector_type(4)));
typedef _Float16 half2v  __attribute__((ext_vector_type(2)));
typedef _Float16 half8   __attribute__((ext_vector_type(8)));

__device__ __forceinline__ half8 cvt8(vfloat4 a, vfloat4 b) {
    half8 r;
    r[0] = (_Float16)a.x; r[1] = (_Float16)a.y; r[2] = (_Float16)a.z; r[3] = (_Float16)a.w;
    r[4] = (_Float16)b.x; r[5] = (_Float16)b.y; r[6] = (_Float16)b.z; r[7] = (_Float16)b.w;
    return r;
}

// ---------------- fused init: W->frag cvt | zero pooled ----------------
__global__ void initcvt_kernel(const float* __restrict__ W0, const float* __restrict__ W1,
                               const float* __restrict__ W2, half8* __restrict__ wf,
                               float* __restrict__ pooled) {
    int b = blockIdx.x;
    if (b < 3) {
        const float* Ws[3] = {W0, W1, W2};
        const float* W = Ws[b];
        half8* outp = wf + (size_t)b * 2048;
        for (int idx = threadIdx.x; idx < 2048; idx += 256) {
            int t = idx >> 9;
            int n = (idx >> 6) & 7;
            int ln = idx & 63;
            int q = ln >> 4, c = ln & 15;
            const float* wp = W + (t * 32 + q * 8) * DIM + n * 16 + c;
            half8 f;
#pragma unroll
            for (int j = 0; j < 8; ++j) f[j] = (_Float16)wp[j * DIM];
            outp[idx] = f;
        }
    } else {
        int k = (b - 3) * 256 + threadIdx.x;
        if (k < NG * DIM) pooled[k] = 0.f;
    }
}

// ---------------- pass1: LDS counting-sort each 4096-edge tile by bin ----------------
// Dense coalesced output chunk + per-chunk bin boundary table. No global atomics.
__launch_bounds__(256, 2)
__global__ void pass1_kernel(const int* __restrict__ src, const int* __restrict__ dst,
                             unsigned* __restrict__ chunks, int* __restrict__ lexg) {
    __shared__ unsigned sorted[CHSZ];
    __shared__ int h[256], lex[257], c2[256];
    int t = threadIdx.x;
    int c = blockIdx.x;
    int e0 = c * CHSZ;
    int nrec = NE - e0; if (nrec > CHSZ) nrec = CHSZ;
    h[t] = 0;
    __syncthreads();
    unsigned myrec[16];
#pragma unroll
    for (int j = 0; j < 16; ++j) {
        int i = t + j * 256;
        if (i < nrec) {
            int e = e0 + i;
            int d = __builtin_nontemporal_load(dst + e);
            int s = __builtin_nontemporal_load(src + e);
            myrec[j] = (unsigned)s | ((unsigned)(d & 255) << 16) | ((unsigned)(d >> 8) << 24);
            atomicAdd(&h[d >> 8], 1);
        } else myrec[j] = 0xFFFFFFFFu;
    }
    __syncthreads();
    if (t < 64) {               // wave-0 exclusive scan of h[0..255]
        int base = t * 4;
        int v0 = h[base], v1 = h[base + 1], v2 = h[base + 2], v3 = h[base + 3];
        int s = v0 + v1 + v2 + v3;
        int inc = s;
#pragma unroll
        for (int o = 1; o < 64; o <<= 1) {
            int u = __shfl_up(inc, o);
            if (t >= o) inc += u;
        }
        int pre = inc - s;
        lex[base] = pre;
        lex[base + 1] = pre + v0;
        lex[base + 2] = pre + v0 + v1;
        lex[base + 3] = pre + v0 + v1 + v2;
        if (t == 63) lex[256] = inc;
    }
    c2[t] = 0;
    __syncthreads();
#pragma unroll
    for (int j = 0; j < 16; ++j) {
        unsigned rec = myrec[j];
        if (rec != 0xFFFFFFFFu) {
            int bb = rec >> 24;
            int pos = lex[bb] + atomicAdd(&c2[bb], 1);
            sorted[pos] = rec;
        }
    }
    __syncthreads();
    for (int j = t; j < nrec; j += 256)
        __builtin_nontemporal_store(sorted[j], chunks + (size_t)c * CHSZ + j);
    if (t < 197) lexg[c * 197 + t] = lex[t];   // boundaries bins 0..196 (196 = total)
}

// ---------------- pass2: per-bin gather + LDS sort by node; padded aligned CSR ----------
__launch_bounds__(256, 1)
__global__ void pass2_kernel(const unsigned* __restrict__ chunks, const int* __restrict__ lexg,
                             unsigned short* __restrict__ edges, int* __restrict__ rowbeg,
                             int* __restrict__ cntn, float* __restrict__ dq) {
    __shared__ unsigned short outb[BINCAP];   // 32 KB
    __shared__ unsigned recs[9472];           // 37 KB (cap: mean 8192, 14 sigma)
    __shared__ int rl[448], co[449];
    __shared__ int h[256], off[257], c2[256];
    int t = threadIdx.x;
    int b = blockIdx.x;   // 0..195
    for (int c = t; c < 448; c += 256)
        rl[c] = (c < NCH) ? (lexg[c * 197 + b + 1] - lexg[c * 197 + b]) : 0;
    __syncthreads();
    if (t < 64) {               // wave-0 exclusive scan of rl[0..447]
        int base = t * 7;
        int v[7], s = 0;
#pragma unroll
        for (int j = 0; j < 7; ++j) { v[j] = rl[base + j]; s += v[j]; }
        int inc = s;
#pragma unroll
        for (int o = 1; o < 64; o <<= 1) {
            int u = __shfl_up(inc, o);
            if (t >= o) inc += u;
        }
        int run = inc - s;
#pragma unroll
        for (int j = 0; j < 7; ++j) { co[base + j] = run; run += v[j]; }
        if (t == 63) co[448] = run;
    }
    h[t] = 0;
    __syncthreads();
    int n = co[448];
    for (int c = t; c < NCH; c += 256) {
        int s0 = lexg[c * 197 + b];
        int len = rl[c];
        int o = co[c];
        const unsigned* cp = chunks + (size_t)c * CHSZ + s0;
        for (int j = 0; j < len; ++j) recs[o + j] = cp[j];
    }
    __syncthreads();
    for (int i = t; i < n; i += 256) atomicAdd(&h[(recs[i] >> 16) & 255], 1);
    __syncthreads();
    if (t < 64) {               // wave-0 exclusive scan of ceil8(h)
        int base = t * 4;
        int v0 = (h[base] + 7) & ~7,     v1 = (h[base + 1] + 7) & ~7;
        int v2 = (h[base + 2] + 7) & ~7, v3 = (h[base + 3] + 7) & ~7;
        int s = v0 + v1 + v2 + v3;
        int inc = s;
#pragma unroll
        for (int o = 1; o < 64; o <<= 1) {
            int u = __shfl_up(inc, o);
            if (t >= o) inc += u;
        }
        int pre = inc - s;
        off[base] = pre;
        off[base + 1] = pre + v0;
        off[base + 2] = pre + v0 + v1;
        off[base + 3] = pre + v0 + v1 + v2;
        if (t == 63) off[256] = inc;
    }
    c2[t] = 0;
    __syncthreads();
    for (int i = t; i < n; i += 256) {
        unsigned rec = recs[i];
        int dl = (rec >> 16) & 255;
        int r = atomicAdd(&c2[dl], 1);
        outb[off[dl] + r] = (unsigned short)(rec & 0xFFFFu);
    }
    __syncthreads();
    int ptot = off[256];
    int B = b * BINCAP;
    for (int i = t; i < ptot; i += 256)
        edges[B + i] = outb[i];
    int node = b * 256 + t;
    if (node < NN) {
        rowbeg[node] = B + off[t];
        int d = h[t];
        cntn[node] = d;
        dq[node] = 1.0f / sqrtf((float)(d + 1));
    }
}

// ---------------- layer-0 GEMM: reads fp32 x directly, converts in-register ----------
__launch_bounds__(256, 2)
__global__ void gemm0_mfma(const float* __restrict__ x, const half8* __restrict__ wfl,
                           _Float16* __restrict__ hout) {
    __shared__ half8 Wf[2048];   // 32 KB
    int tid = threadIdx.x;
    for (int idx = tid; idx < 2048; idx += 256) Wf[idx] = wfl[idx];
    __syncthreads();
    int wid = tid >> 6, lane = tid & 63;
    int q = lane >> 4, m = lane & 15;
    int r0 = blockIdx.x * 64 + wid * 16;
    int arow = r0 + m;
    if (arow > NN - 1) arow = NN - 1;
    const vfloat4* ap = (const vfloat4*)(x + (size_t)arow * DIM + q * 8);
    half8 a0 = cvt8(ap[0],  ap[1]);
    half8 a1 = cvt8(ap[8],  ap[9]);
    half8 a2 = cvt8(ap[16], ap[17]);
    half8 a3 = cvt8(ap[24], ap[25]);
    floatx4 acc[8];
#pragma unroll
    for (int n = 0; n < 8; ++n) acc[n] = (floatx4){0.f, 0.f, 0.f, 0.f};
#pragma unroll
    for (int n = 0; n < 8; ++n)
        acc[n] = __builtin_amdgcn_mfma_f32_16x16x32_f16(a0, Wf[(0 * 8 + n) * 64 + lane], acc[n], 0, 0, 0);
#pragma unroll
    for (int n = 0; n < 8; ++n)
        acc[n] = __builtin_amdgcn_mfma_f32_16x16x32_f16(a1, Wf[(1 * 8 + n) * 64 + lane], acc[n], 0, 0, 0);
#pragma unroll
    for (int n = 0; n < 8; ++n)
        acc[n] = __builtin_amdgcn_mfma_f32_16x16x32_f16(a2, Wf[(2 * 8 + n) * 64 + lane], acc[n], 0, 0, 0);
#pragma unroll
    for (int n = 0; n < 8; ++n)
        acc[n] = __builtin_amdgcn_mfma_f32_16x16x32_f16(a3, Wf[(3 * 8 + n) * 64 + lane], acc[n], 0, 0, 0);
#pragma unroll
    for (int n = 0; n < 8; ++n) {
#pragma unroll
        for (int r = 0; r < 4; ++r) {
            int row = r0 + q * 4 + r;
            if (row < NN)
                hout[(size_t)row * DIM + n * 16 + m] = (_Float16)acc[n][r];
        }
    }
}

// ---------------- GEMM via MFMA: one 64-row group per block (fp16 input) ----------------
__launch_bounds__(256, 2)
__global__ void gemm_mfma(const _Float16* __restrict__ yin, const half8* __restrict__ wfl,
                          _Float16* __restrict__ hout) {
    __shared__ half8 Wf[2048];   // 32 KB
    int tid = threadIdx.x;
    for (int idx = tid; idx < 2048; idx += 256) Wf[idx] = wfl[idx];
    __syncthreads();
    int wid = tid >> 6, lane = tid & 63;
    int q = lane >> 4, m = lane & 15;
    int r0 = blockIdx.x * 64 + wid * 16;
    int arow = r0 + m;
    if (arow > NN - 1) arow = NN - 1;
    const half8* ap = (const half8*)(yin + (size_t)arow * DIM + q * 8);
    half8 a0 = ap[0], a1 = ap[4], a2 = ap[8], a3 = ap[12];
    floatx4 acc[8];
#pragma unroll
    for (int n = 0; n < 8; ++n) acc[n] = (floatx4){0.f, 0.f, 0.f, 0.f};
#pragma unroll
    for (int n = 0; n < 8; ++n)
        acc[n] = __builtin_amdgcn_mfma_f32_16x16x32_f16(a0, Wf[(0 * 8 + n) * 64 + lane], acc[n], 0, 0, 0);
#pragma unroll
    for (int n = 0; n < 8; ++n)
        acc[n] = __builtin_amdgcn_mfma_f32_16x16x32_f16(a1, Wf[(1 * 8 + n) * 64 + lane], acc[n], 0, 0, 0);
#pragma unroll
    for (int n = 0; n < 8; ++n)
        acc[n] = __builtin_amdgcn_mfma_f32_16x16x32_f16(a2, Wf[(2 * 8 + n) * 64 + lane], acc[n], 0, 0, 0);
#pragma unroll
    for (int n = 0; n < 8; ++n)
        acc[n] = __builtin_amdgcn_mfma_f32_16x16x32_f16(a3, Wf[(3 * 8 + n) * 64 + lane], acc[n], 0, 0, 0);
#pragma unroll
    for (int n = 0; n < 8; ++n) {
#pragma unroll
        for (int r = 0; r < 4; ++r) {
            int row = r0 + q * 4 + r;
            if (row < NN)
                hout[(size_t)row * DIM + n * 16 + m] = (_Float16)acc[n][r];
        }
    }
}

// ---------------- fused conv: aligned padded-CSR 16-deep gather + norm + L2norm/ReLU ----
__launch_bounds__(256, 8)
__global__ void conv_kernel(const half2v* __restrict__ h2, const float* __restrict__ bias,
                            const int* __restrict__ rowbeg, const int* __restrict__ cntn,
                            const unsigned short* __restrict__ edges, const float* __restrict__ dq,
                            half2v* __restrict__ out, const int* __restrict__ batch,
                            float* __restrict__ pooled, int do_pool) {
    int wid = threadIdx.x >> 6;
    int lane = threadIdx.x & 63;
    int node = blockIdx.x * 4 + wid;
    if (node >= NN) return;
    int deg = cntn[node];
    const unsigned short* ep = edges + rowbeg[node];   // 16B-aligned (8-slot padding)
    float ax = 0.f, ay = 0.f;
    int e = 0;
    for (; e + 16 <= deg; e += 16) {
        vuint4 pa = __builtin_nontemporal_load((const vuint4*)(ep + e));
        vuint4 pb = __builtin_nontemporal_load((const vuint4*)(ep + e + 8));
        unsigned s[16];
        s[0] = pa.x & 0xFFFFu;  s[1] = pa.x >> 16;
        s[2] = pa.y & 0xFFFFu;  s[3] = pa.y >> 16;
        s[4] = pa.z & 0xFFFFu;  s[5] = pa.z >> 16;
        s[6] = pa.w & 0xFFFFu;  s[7] = pa.w >> 16;
        s[8] = pb.x & 0xFFFFu;  s[9] = pb.x >> 16;
        s[10] = pb.y & 0xFFFFu; s[11] = pb.y >> 16;
        s[12] = pb.z & 0xFFFFu; s[13] = pb.z >> 16;
        s[14] = pb.w & 0xFFFFu; s[15] = pb.w >> 16;
        float dv[16];
        half2v hv[16];
#pragma unroll
        for (int j = 0; j < 16; ++j) {
            dv[j] = dq[s[j]];
            hv[j] = h2[(size_t)s[j] * 64 + lane];
        }
#pragma unroll
        for (int j = 0; j < 16; ++j) {
            ax += dv[j] * (float)hv[j].x;
            ay += dv[j] * (float)hv[j].y;
        }
    }
    for (; e + 8 <= deg; e += 8) {
        vuint4 pa = __builtin_nontemporal_load((const vuint4*)(ep + e));
        unsigned s[8];
        s[0] = pa.x & 0xFFFFu; s[1] = pa.x >> 16;
        s[2] = pa.y & 0xFFFFu; s[3] = pa.y >> 16;
        s[4] = pa.z & 0xFFFFu; s[5] = pa.z >> 16;
        s[6] = pa.w & 0xFFFFu; s[7] = pa.w >> 16;
        float dv[8];
        half2v hv[8];
#pragma unroll
        for (int j = 0; j < 8; ++j) {
            dv[j] = dq[s[j]];
            hv[j] = h2[(size_t)s[j] * 64 + lane];
        }
#pragma unroll
        for (int j = 0; j < 8; ++j) {
            ax += dv[j] * (float)hv[j].x;
            ay += dv[j] * (float)hv[j].y;
        }
    }
    for (; e < deg; ++e) {
        unsigned s = ep[e];
        float ds = dq[s];
        half2v v = h2[(size_t)s * 64 + lane];
        ax += ds * (float)v.x;
        ay += ds * (float)v.y;
    }
    float dqd = dq[node];
    float sn = dqd * dqd;      // selfn = 1/deg = dq^2
    half2v hvn = h2[(size_t)node * 64 + lane];
    ax = ax * dqd + sn * (float)hvn.x + bias[2 * lane];
    ay = ay * dqd + sn * (float)hvn.y + bias[2 * lane + 1];
    float ss = ax * ax + ay * ay;
#pragma unroll
    for (int off = 32; off; off >>= 1) ss += __shfl_xor(ss, off);
    float inv = 1.0f / fmaxf(sqrtf(ss), 1e-12f);
    float ox = fmaxf(ax * inv, 0.f);
    float oy = fmaxf(ay * inv, 0.f);
    if (!do_pool) {
        half2v o;
        o.x = (_Float16)ox;
        o.y = (_Float16)oy;
        out[(size_t)node * 64 + lane] = o;   // cached: y stays L2-hot for next GEMM
    } else {
        int g = batch[node];
        atomicAdd(&pooled[g * DIM + 2 * lane], ox);
        atomicAdd(&pooled[g * DIM + 2 * lane + 1], oy);
    }
}

// ---------------- head: z = relu(pooled@W1+b1); logits = z@W2+b2 ----------------
__launch_bounds__(128)
__global__ void head_kernel(const float* __restrict__ pooled, const float* __restrict__ w1,
                            const float* __restrict__ b1, const float* __restrict__ w2,
                            const float* __restrict__ b2, float* __restrict__ out) {
    __shared__ float sp[DIM];
    __shared__ float red[4];
    int g = blockIdx.x;
    int k = threadIdx.x;
    sp[k] = pooled[g * DIM + k];
    __syncthreads();
    float acc = b1[k];
#pragma unroll 8
    for (int j = 0; j < DIM; ++j) acc += sp[j] * w1[j * DIM + k];
    float z = fmaxf(acc, 0.f);
    float p0 = z * w2[k * 2 + 0];
    float p1 = z * w2[k * 2 + 1];
#pragma unroll
    for (int off = 32; off; off >>= 1) {
        p0 += __shfl_xor(p0, off);
        p1 += __shfl_xor(p1, off);
    }
    if ((k & 63) == 0) {
        red[(k >> 6) * 2 + 0] = p0;
        red[(k >> 6) * 2 + 1] = p1;
    }
    __syncthreads();
    if (k == 0) {
        out[g * 2 + 0] = red[0] + red[2] + b2[0];
        out[g * 2 + 1] = red[1] + red[3] + b2[1];
    }
}

extern "C" void kernel_launch(void* const* d_in, const int* in_sizes, int n_in,
                              void* d_out, int out_size, void* d_ws, size_t ws_size,
                              hipStream_t stream) {
    const float* x    = (const float*)d_in[0];
    const int* eidx   = (const int*)d_in[1];
    const int* batch  = (const int*)d_in[2];
    const float* W0   = (const float*)d_in[3];
    const float* b0   = (const float*)d_in[4];
    const float* W1   = (const float*)d_in[5];
    const float* b1   = (const float*)d_in[6];
    const float* W2   = (const float*)d_in[7];
    const float* b2   = (const float*)d_in[8];
    const float* l1w  = (const float*)d_in[9];
    const float* l1b  = (const float*)d_in[10];
    const float* l2w  = (const float*)d_in[11];
    const float* l2b  = (const float*)d_in[12];
    float* out = (float*)d_out;

    char* w = (char*)d_ws;
    float* dq     = (float*)w; w += (size_t)NN * 4;
    int*   rowbeg = (int*)w;   w += (size_t)NN * 4;
    int*   cntn   = (int*)w;   w += (size_t)NN * 4;
    int*   lexg   = (int*)w;   w += (size_t)NCH * 197 * 4;           // 308 KB
    unsigned* chunks = (unsigned*)w; w += (size_t)NCH * CHSZ * 4;    // 6.4 MB
    unsigned short* edges = (unsigned short*)w; w += (size_t)NBINS * BINCAP * 2;  // 6.4 MB
    half8* wf     = (half8*)w; w += (size_t)3 * 2048 * 16;
    _Float16* bufh = (_Float16*)w; w += (size_t)NN * DIM * 2;   // h (gemm out, gathered)
    _Float16* bufy = (_Float16*)w; w += (size_t)NN * DIM * 2;   // y (conv out)
    float* pooled = (float*)w; w += (size_t)NG * DIM * 4;

    const int* src = eidx;
    const int* dst = eidx + NE;

    initcvt_kernel<<<3 + (NG * DIM + 255) / 256, 256, 0, stream>>>(W0, W1, W2, wf, pooled);
    pass1_kernel<<<NCH, 256, 0, stream>>>(src, dst, chunks, lexg);
    pass2_kernel<<<NBINS, 256, 0, stream>>>(chunks, lexg, edges, rowbeg, cntn, dq);

    const int CG = (NN + 3) / 4;        // 12500 blocks, one wave per node
    const int GG = (NN + 63) / 64;      // 782 blocks, one 64-row group per block

    gemm0_mfma<<<GG, 256, 0, stream>>>(x, wf, bufh);
    conv_kernel<<<CG, 256, 0, stream>>>((const half2v*)bufh, b0, rowbeg, cntn, edges, dq,
                                        (half2v*)bufy, batch, pooled, 0);
    gemm_mfma<<<GG, 256, 0, stream>>>(bufy, wf + 2048, bufh);
    conv_kernel<<<CG, 256, 0, stream>>>((const half2v*)bufh, b1, rowbeg, cntn, edges, dq,
                                        (half2v*)bufy, batch, pooled, 0);
    gemm_mfma<<<GG, 256, 0, stream>>>(bufy, wf + 4096, bufh);
    conv_kernel<<<CG, 256, 0, stream>>>((const half2v*)bufh, b2, rowbeg, cntn, edges, dq,
                                        (half2v*)bufy, batch, pooled, 1);
    head_kernel<<<NG, 128, 0, stream>>>(pooled, l1w, l1b, l2w, l2b, out);
}

// Round 16
// 470.387 us; speedup vs baseline: 5.9346x; 1.1071x over previous
//
#include <hip/hip_runtime.h>

#define NN 50000
#define NE 1600000
#define DIM 128
#define NG  512
#define NCH 391        // ceil(NE/4096) edge chunks
#define CHSZ 4096
#define NBINS 196      // bin = dst >> 8 (dst < 50000 -> 0..195)
#define BINCAP 16384   // padded CSR slots per bin (expected ~10000)

typedef int      vint4   __attribute__((ext_vector_type(4)));
typedef float    vfloat4 __attribute__((ext_vector_type(4)));
typedef float    floatx4 __attribute__((ext_vector_type(4)));
typedef unsigned vuint4  __attribute__((ext_vector_type(4)));
typedef _Float16 half2v  __attribute__((ext_vector_type(2)));
typedef _Float16 half8   __attribute__((ext_vector_type(8)));

__device__ __forceinline__ half8 cvt8(vfloat4 a, vfloat4 b) {
    half8 r;
    r[0] = (_Float16)a.x; r[1] = (_Float16)a.y; r[2] = (_Float16)a.z; r[3] = (_Float16)a.w;
    r[4] = (_Float16)b.x; r[5] = (_Float16)b.y; r[6] = (_Float16)b.z; r[7] = (_Float16)b.w;
    return r;
}

// ---------------- fused init: W->frag cvt | zero pooled ----------------
__global__ void initcvt_kernel(const float* __restrict__ W0, const float* __restrict__ W1,
                               const float* __restrict__ W2, half8* __restrict__ wf,
                               float* __restrict__ pooled) {
    int b = blockIdx.x;
    if (b < 3) {
        const float* Ws[3] = {W0, W1, W2};
        const float* W = Ws[b];
        half8* outp = wf + (size_t)b * 2048;
        for (int idx = threadIdx.x; idx < 2048; idx += 256) {
            int t = idx >> 9;
            int n = (idx >> 6) & 7;
            int ln = idx & 63;
            int q = ln >> 4, c = ln & 15;
            const float* wp = W + (t * 32 + q * 8) * DIM + n * 16 + c;
            half8 f;
#pragma unroll
            for (int j = 0; j < 8; ++j) f[j] = (_Float16)wp[j * DIM];
            outp[idx] = f;
        }
    } else {
        int k = (b - 3) * 256 + threadIdx.x;
        if (k < NG * DIM) pooled[k] = 0.f;
    }
}

// ---------------- pass1: LDS counting-sort each 4096-edge tile by bin ----------------
__launch_bounds__(256, 2)
__global__ void pass1_kernel(const int* __restrict__ src, const int* __restrict__ dst,
                             unsigned* __restrict__ chunks, int* __restrict__ lexg) {
    __shared__ unsigned sorted[CHSZ];
    __shared__ int h[256], lex[257], c2[256];
    int t = threadIdx.x;
    int c = blockIdx.x;
    int e0 = c * CHSZ;
    int nrec = NE - e0; if (nrec > CHSZ) nrec = CHSZ;
    h[t] = 0;
    __syncthreads();
    unsigned myrec[16];
#pragma unroll
    for (int j = 0; j < 16; ++j) {
        int i = t + j * 256;
        if (i < nrec) {
            int e = e0 + i;
            int d = __builtin_nontemporal_load(dst + e);
            int s = __builtin_nontemporal_load(src + e);
            myrec[j] = (unsigned)s | ((unsigned)(d & 255) << 16) | ((unsigned)(d >> 8) << 24);
            atomicAdd(&h[d >> 8], 1);
        } else myrec[j] = 0xFFFFFFFFu;
    }
    __syncthreads();
    if (t < 64) {               // wave-0 exclusive scan of h[0..255]
        int base = t * 4;
        int v0 = h[base], v1 = h[base + 1], v2 = h[base + 2], v3 = h[base + 3];
        int s = v0 + v1 + v2 + v3;
        int inc = s;
#pragma unroll
        for (int o = 1; o < 64; o <<= 1) {
            int u = __shfl_up(inc, o);
            if (t >= o) inc += u;
        }
        int pre = inc - s;
        lex[base] = pre;
        lex[base + 1] = pre + v0;
        lex[base + 2] = pre + v0 + v1;
        lex[base + 3] = pre + v0 + v1 + v2;
        if (t == 63) lex[256] = inc;
    }
    c2[t] = 0;
    __syncthreads();
#pragma unroll
    for (int j = 0; j < 16; ++j) {
        unsigned rec = myrec[j];
        if (rec != 0xFFFFFFFFu) {
            int bb = rec >> 24;
            int pos = lex[bb] + atomicAdd(&c2[bb], 1);
            sorted[pos] = rec;
        }
    }
    __syncthreads();
    for (int j = t; j < nrec; j += 256)
        __builtin_nontemporal_store(sorted[j], chunks + (size_t)c * CHSZ + j);
    if (t < 197) lexg[c * 197 + t] = lex[t];
}

// ---------------- pass2: per-bin gather + LDS sort by node; padded aligned CSR ----------
__launch_bounds__(256, 1)
__global__ void pass2_kernel(const unsigned* __restrict__ chunks, const int* __restrict__ lexg,
                             unsigned short* __restrict__ edges, int* __restrict__ rowbeg,
                             int* __restrict__ cntn, float* __restrict__ dq) {
    __shared__ unsigned short outb[BINCAP];   // 32 KB
    __shared__ unsigned recs[9472];           // 37 KB (cap: mean 8192, 14 sigma)
    __shared__ int rl[448], co[449];
    __shared__ int h[256], off[257], c2[256];
    int t = threadIdx.x;
    int b = blockIdx.x;   // 0..195
    for (int c = t; c < 448; c += 256)
        rl[c] = (c < NCH) ? (lexg[c * 197 + b + 1] - lexg[c * 197 + b]) : 0;
    __syncthreads();
    if (t < 64) {               // wave-0 exclusive scan of rl[0..447]
        int base = t * 7;
        int v[7], s = 0;
#pragma unroll
        for (int j = 0; j < 7; ++j) { v[j] = rl[base + j]; s += v[j]; }
        int inc = s;
#pragma unroll
        for (int o = 1; o < 64; o <<= 1) {
            int u = __shfl_up(inc, o);
            if (t >= o) inc += u;
        }
        int run = inc - s;
#pragma unroll
        for (int j = 0; j < 7; ++j) { co[base + j] = run; run += v[j]; }
        if (t == 63) co[448] = run;
    }
    h[t] = 0;
    __syncthreads();
    int n = co[448];
    for (int c = t; c < NCH; c += 256) {
        int s0 = lexg[c * 197 + b];
        int len = rl[c];
        int o = co[c];
        const unsigned* cp = chunks + (size_t)c * CHSZ + s0;
        for (int j = 0; j < len; ++j) recs[o + j] = cp[j];
    }
    __syncthreads();
    for (int i = t; i < n; i += 256) atomicAdd(&h[(recs[i] >> 16) & 255], 1);
    __syncthreads();
    if (t < 64) {               // wave-0 exclusive scan of ceil8(h)
        int base = t * 4;
        int v0 = (h[base] + 7) & ~7,     v1 = (h[base + 1] + 7) & ~7;
        int v2 = (h[base + 2] + 7) & ~7, v3 = (h[base + 3] + 7) & ~7;
        int s = v0 + v1 + v2 + v3;
        int inc = s;
#pragma unroll
        for (int o = 1; o < 64; o <<= 1) {
            int u = __shfl_up(inc, o);
            if (t >= o) inc += u;
        }
        int pre = inc - s;
        off[base] = pre;
        off[base + 1] = pre + v0;
        off[base + 2] = pre + v0 + v1;
        off[base + 3] = pre + v0 + v1 + v2;
        if (t == 63) off[256] = inc;
    }
    c2[t] = 0;
    __syncthreads();
    for (int i = t; i < n; i += 256) {
        unsigned rec = recs[i];
        int dl = (rec >> 16) & 255;
        int r = atomicAdd(&c2[dl], 1);
        outb[off[dl] + r] = (unsigned short)(rec & 0xFFFFu);
    }
    __syncthreads();
    int ptot = off[256];
    int B = b * BINCAP;
    for (int i = t; i < ptot; i += 256)
        edges[B + i] = outb[i];
    int node = b * 256 + t;
    if (node < NN) {
        rowbeg[node] = B + off[t];
        int d = h[t];
        cntn[node] = d;
        dq[node] = 1.0f / sqrtf((float)(d + 1));
    }
}

// ---------------- layer-0 GEMM: reads fp32 x directly, converts in-register ----------
__launch_bounds__(256, 2)
__global__ void gemm0_mfma(const float* __restrict__ x, const half8* __restrict__ wfl,
                           _Float16* __restrict__ hout) {
    __shared__ half8 Wf[2048];   // 32 KB
    int tid = threadIdx.x;
    for (int idx = tid; idx < 2048; idx += 256) Wf[idx] = wfl[idx];
    __syncthreads();
    int wid = tid >> 6, lane = tid & 63;
    int q = lane >> 4, m = lane & 15;
    int r0 = blockIdx.x * 64 + wid * 16;
    int arow = r0 + m;
    if (arow > NN - 1) arow = NN - 1;
    const vfloat4* ap = (const vfloat4*)(x + (size_t)arow * DIM + q * 8);
    half8 a0 = cvt8(ap[0],  ap[1]);
    half8 a1 = cvt8(ap[8],  ap[9]);
    half8 a2 = cvt8(ap[16], ap[17]);
    half8 a3 = cvt8(ap[24], ap[25]);
    floatx4 acc[8];
#pragma unroll
    for (int n = 0; n < 8; ++n) acc[n] = (floatx4){0.f, 0.f, 0.f, 0.f};
#pragma unroll
    for (int n = 0; n < 8; ++n)
        acc[n] = __builtin_amdgcn_mfma_f32_16x16x32_f16(a0, Wf[(0 * 8 + n) * 64 + lane], acc[n], 0, 0, 0);
#pragma unroll
    for (int n = 0; n < 8; ++n)
        acc[n] = __builtin_amdgcn_mfma_f32_16x16x32_f16(a1, Wf[(1 * 8 + n) * 64 + lane], acc[n], 0, 0, 0);
#pragma unroll
    for (int n = 0; n < 8; ++n)
        acc[n] = __builtin_amdgcn_mfma_f32_16x16x32_f16(a2, Wf[(2 * 8 + n) * 64 + lane], acc[n], 0, 0, 0);
#pragma unroll
    for (int n = 0; n < 8; ++n)
        acc[n] = __builtin_amdgcn_mfma_f32_16x16x32_f16(a3, Wf[(3 * 8 + n) * 64 + lane], acc[n], 0, 0, 0);
#pragma unroll
    for (int n = 0; n < 8; ++n) {
#pragma unroll
        for (int r = 0; r < 4; ++r) {
            int row = r0 + q * 4 + r;
            if (row < NN)
                hout[(size_t)row * DIM + n * 16 + m] = (_Float16)acc[n][r];
        }
    }
}

// ---------------- GEMM via MFMA: one 64-row group per block (fp16 input) ----------------
__launch_bounds__(256, 2)
__global__ void gemm_mfma(const _Float16* __restrict__ yin, const half8* __restrict__ wfl,
                          _Float16* __restrict__ hout) {
    __shared__ half8 Wf[2048];   // 32 KB
    int tid = threadIdx.x;
    for (int idx = tid; idx < 2048; idx += 256) Wf[idx] = wfl[idx];
    __syncthreads();
    int wid = tid >> 6, lane = tid & 63;
    int q = lane >> 4, m = lane & 15;
    int r0 = blockIdx.x * 64 + wid * 16;
    int arow = r0 + m;
    if (arow > NN - 1) arow = NN - 1;
    const half8* ap = (const half8*)(yin + (size_t)arow * DIM + q * 8);
    half8 a0 = ap[0], a1 = ap[4], a2 = ap[8], a3 = ap[12];
    floatx4 acc[8];
#pragma unroll
    for (int n = 0; n < 8; ++n) acc[n] = (floatx4){0.f, 0.f, 0.f, 0.f};
#pragma unroll
    for (int n = 0; n < 8; ++n)
        acc[n] = __builtin_amdgcn_mfma_f32_16x16x32_f16(a0, Wf[(0 * 8 + n) * 64 + lane], acc[n], 0, 0, 0);
#pragma unroll
    for (int n = 0; n < 8; ++n)
        acc[n] = __builtin_amdgcn_mfma_f32_16x16x32_f16(a1, Wf[(1 * 8 + n) * 64 + lane], acc[n], 0, 0, 0);
#pragma unroll
    for (int n = 0; n < 8; ++n)
        acc[n] = __builtin_amdgcn_mfma_f32_16x16x32_f16(a2, Wf[(2 * 8 + n) * 64 + lane], acc[n], 0, 0, 0);
#pragma unroll
    for (int n = 0; n < 8; ++n)
        acc[n] = __builtin_amdgcn_mfma_f32_16x16x32_f16(a3, Wf[(3 * 8 + n) * 64 + lane], acc[n], 0, 0, 0);
#pragma unroll
    for (int n = 0; n < 8; ++n) {
#pragma unroll
        for (int r = 0; r < 4; ++r) {
            int row = r0 + q * 4 + r;
            if (row < NN)
                hout[(size_t)row * DIM + n * 16 + m] = (_Float16)acc[n][r];
        }
    }
}

// ---------------- fused conv: aligned padded-CSR 16-deep gather + norm + L2norm/ReLU ----
__launch_bounds__(256, 8)
__global__ void conv_kernel(const half2v* __restrict__ h2, const float* __restrict__ bias,
                            const int* __restrict__ rowbeg, const int* __restrict__ cntn,
                            const unsigned short* __restrict__ edges, const float* __restrict__ dq,
                            half2v* __restrict__ out, const int* __restrict__ batch,
                            float* __restrict__ pooled, int do_pool) {
    int wid = threadIdx.x >> 6;
    int lane = threadIdx.x & 63;
    int node = blockIdx.x * 4 + wid;
    if (node >= NN) return;
    int deg = cntn[node];
    const unsigned short* ep = edges + rowbeg[node];   // 16B-aligned (8-slot padding)
    float ax = 0.f, ay = 0.f;
    int e = 0;
    for (; e + 16 <= deg; e += 16) {
        vuint4 pa = __builtin_nontemporal_load((const vuint4*)(ep + e));
        vuint4 pb = __builtin_nontemporal_load((const vuint4*)(ep + e + 8));
        unsigned s[16];
        s[0] = pa.x & 0xFFFFu;  s[1] = pa.x >> 16;
        s[2] = pa.y & 0xFFFFu;  s[3] = pa.y >> 16;
        s[4] = pa.z & 0xFFFFu;  s[5] = pa.z >> 16;
        s[6] = pa.w & 0xFFFFu;  s[7] = pa.w >> 16;
        s[8] = pb.x & 0xFFFFu;  s[9] = pb.x >> 16;
        s[10] = pb.y & 0xFFFFu; s[11] = pb.y >> 16;
        s[12] = pb.z & 0xFFFFu; s[13] = pb.z >> 16;
        s[14] = pb.w & 0xFFFFu; s[15] = pb.w >> 16;
        float dv[16];
        half2v hv[16];
#pragma unroll
        for (int j = 0; j < 16; ++j) {
            dv[j] = dq[s[j]];
            hv[j] = h2[(size_t)s[j] * 64 + lane];
        }
#pragma unroll
        for (int j = 0; j < 16; ++j) {
            ax += dv[j] * (float)hv[j].x;
            ay += dv[j] * (float)hv[j].y;
        }
    }
    for (; e + 8 <= deg; e += 8) {
        vuint4 pa = __builtin_nontemporal_load((const vuint4*)(ep + e));
        unsigned s[8];
        s[0] = pa.x & 0xFFFFu; s[1] = pa.x >> 16;
        s[2] = pa.y & 0xFFFFu; s[3] = pa.y >> 16;
        s[4] = pa.z & 0xFFFFu; s[5] = pa.z >> 16;
        s[6] = pa.w & 0xFFFFu; s[7] = pa.w >> 16;
        float dv[8];
        half2v hv[8];
#pragma unroll
        for (int j = 0; j < 8; ++j) {
            dv[j] = dq[s[j]];
            hv[j] = h2[(size_t)s[j] * 64 + lane];
        }
#pragma unroll
        for (int j = 0; j < 8; ++j) {
            ax += dv[j] * (float)hv[j].x;
            ay += dv[j] * (float)hv[j].y;
        }
    }
    for (; e < deg; ++e) {
        unsigned s = ep[e];
        float ds = dq[s];
        half2v v = h2[(size_t)s * 64 + lane];
        ax += ds * (float)v.x;
        ay += ds * (float)v.y;
    }
    float dqd = dq[node];
    float sn = dqd * dqd;      // selfn = 1/deg = dq^2
    half2v hvn = h2[(size_t)node * 64 + lane];
    ax = ax * dqd + sn * (float)hvn.x + bias[2 * lane];
    ay = ay * dqd + sn * (float)hvn.y + bias[2 * lane + 1];
    float ss = ax * ax + ay * ay;
#pragma unroll
    for (int off = 32; off; off >>= 1) ss += __shfl_xor(ss, off);
    float inv = 1.0f / fmaxf(sqrtf(ss), 1e-12f);
    float ox = fmaxf(ax * inv, 0.f);
    float oy = fmaxf(ay * inv, 0.f);
    if (!do_pool) {
        half2v o;
        o.x = (_Float16)ox;
        o.y = (_Float16)oy;
        out[(size_t)node * 64 + lane] = o;   // cached: y stays L2-hot for next GEMM
    } else {
        int g = batch[node];
        atomicAdd(&pooled[g * DIM + 2 * lane], ox);
        atomicAdd(&pooled[g * DIM + 2 * lane + 1], oy);
    }
}

// ---------------- head: z = relu(pooled@W1+b1); logits = z@W2+b2 ----------------
__launch_bounds__(128)
__global__ void head_kernel(const float* __restrict__ pooled, const float* __restrict__ w1,
                            const float* __restrict__ b1, const float* __restrict__ w2,
                            const float* __restrict__ b2, float* __restrict__ out) {
    __shared__ float sp[DIM];
    __shared__ float red[4];
    int g = blockIdx.x;
    int k = threadIdx.x;
    sp[k] = pooled[g * DIM + k];
    __syncthreads();
    float acc = b1[k];
#pragma unroll 8
    for (int j = 0; j < DIM; ++j) acc += sp[j] * w1[j * DIM + k];
    float z = fmaxf(acc, 0.f);
    float p0 = z * w2[k * 2 + 0];
    float p1 = z * w2[k * 2 + 1];
#pragma unroll
    for (int off = 32; off; off >>= 1) {
        p0 += __shfl_xor(p0, off);
        p1 += __shfl_xor(p1, off);
    }
    if ((k & 63) == 0) {
        red[(k >> 6) * 2 + 0] = p0;
        red[(k >> 6) * 2 + 1] = p1;
    }
    __syncthreads();
    if (k == 0) {
        out[g * 2 + 0] = red[0] + red[2] + b2[0];
        out[g * 2 + 1] = red[1] + red[3] + b2[1];
    }
}

extern "C" void kernel_launch(void* const* d_in, const int* in_sizes, int n_in,
                              void* d_out, int out_size, void* d_ws, size_t ws_size,
                              hipStream_t stream) {
    const float* x    = (const float*)d_in[0];
    const int* eidx   = (const int*)d_in[1];
    const int* batch  = (const int*)d_in[2];
    const float* W0   = (const float*)d_in[3];
    const float* b0   = (const float*)d_in[4];
    const float* W1   = (const float*)d_in[5];
    const float* b1   = (const float*)d_in[6];
    const float* W2   = (const float*)d_in[7];
    const float* b2   = (const float*)d_in[8];
    const float* l1w  = (const float*)d_in[9];
    const float* l1b  = (const float*)d_in[10];
    const float* l2w  = (const float*)d_in[11];
    const float* l2b  = (const float*)d_in[12];
    float* out = (float*)d_out;

    // all allocations rounded up to 256 B so every buffer is line-aligned
    #define ALIGN256(v) (((size_t)(v) + 255) & ~(size_t)255)
    char* w = (char*)d_ws;
    float* dq     = (float*)w; w += ALIGN256((size_t)NN * 4);
    int*   rowbeg = (int*)w;   w += ALIGN256((size_t)NN * 4);
    int*   cntn   = (int*)w;   w += ALIGN256((size_t)NN * 4);
    int*   lexg   = (int*)w;   w += ALIGN256((size_t)NCH * 197 * 4);
    unsigned* chunks = (unsigned*)w; w += ALIGN256((size_t)NCH * CHSZ * 4);
    unsigned short* edges = (unsigned short*)w; w += ALIGN256((size_t)NBINS * BINCAP * 2);
    half8* wf     = (half8*)w; w += ALIGN256((size_t)3 * 2048 * 16);
    _Float16* bufh = (_Float16*)w; w += ALIGN256((size_t)NN * DIM * 2);
    _Float16* bufy = (_Float16*)w; w += ALIGN256((size_t)NN * DIM * 2);
    float* pooled = (float*)w; w += ALIGN256((size_t)NG * DIM * 4);

    const int* src = eidx;
    const int* dst = eidx + NE;

    initcvt_kernel<<<3 + (NG * DIM + 255) / 256, 256, 0, stream>>>(W0, W1, W2, wf, pooled);
    pass1_kernel<<<NCH, 256, 0, stream>>>(src, dst, chunks, lexg);
    pass2_kernel<<<NBINS, 256, 0, stream>>>(chunks, lexg, edges, rowbeg, cntn, dq);

    const int CG = (NN + 3) / 4;        // 12500 blocks, one wave per node
    const int GG = (NN + 63) / 64;      // 782 blocks, one 64-row group per block

    gemm0_mfma<<<GG, 256, 0, stream>>>(x, wf, bufh);
    conv_kernel<<<CG, 256, 0, stream>>>((const half2v*)bufh, b0, rowbeg, cntn, edges, dq,
                                        (half2v*)bufy, batch, pooled, 0);
    gemm_mfma<<<GG, 256, 0, stream>>>(bufy, wf + 2048, bufh);
    conv_kernel<<<CG, 256, 0, stream>>>((const half2v*)bufh, b1, rowbeg, cntn, edges, dq,
                                        (half2v*)bufy, batch, pooled, 0);
    gemm_mfma<<<GG, 256, 0, stream>>>(bufy, wf + 4096, bufh);
    conv_kernel<<<CG, 256, 0, stream>>>((const half2v*)bufh, b2, rowbeg, cntn, edges, dq,
                                        (half2v*)bufy, batch, pooled, 1);
    head_kernel<<<NG, 128, 0, stream>>>(pooled, l1w, l1b, l2w, l2b, out);
}

// Round 17
// 369.578 us; speedup vs baseline: 7.5533x; 1.2728x over previous
//
#include <hip/hip_runtime.h>

#define NN 50000
#define NE 1600000
#define DIM 128
#define NG  512
#define NCH 391        // ceil(NE/4096) edge chunks
#define CHSZ 4096
#define NBINS 196      // bin = dst >> 8 (dst < 50000 -> 0..195)
#define BINCAP 16384   // padded CSR slots per bin (expected ~10000)

typedef int      vint4   __attribute__((ext_vector_type(4)));
typedef float    vfloat4 __attribute__((ext_vector_type(4)));
typedef float    floatx4 __attribute__((ext_vector_type(4)));
typedef unsigned vuint4  __attribute__((ext_vector_type(4)));
typedef _Float16 half2v  __attribute__((ext_vector_type(2)));
typedef _Float16 half8   __attribute__((ext_vector_type(8)));

__device__ __forceinline__ half8 cvt8(vfloat4 a, vfloat4 b) {
    half8 r;
    r[0] = (_Float16)a.x; r[1] = (_Float16)a.y; r[2] = (_Float16)a.z; r[3] = (_Float16)a.w;
    r[4] = (_Float16)b.x; r[5] = (_Float16)b.y; r[6] = (_Float16)b.z; r[7] = (_Float16)b.w;
    return r;
}

// ---------------- fused init: W->frag cvt | zero pooled ----------------
__global__ void initcvt_kernel(const float* __restrict__ W0, const float* __restrict__ W1,
                               const float* __restrict__ W2, half8* __restrict__ wf,
                               float* __restrict__ pooled) {
    int b = blockIdx.x;
    if (b < 3) {
        const float* Ws[3] = {W0, W1, W2};
        const float* W = Ws[b];
        half8* outp = wf + (size_t)b * 2048;
        for (int idx = threadIdx.x; idx < 2048; idx += 256) {
            int t = idx >> 9;
            int n = (idx >> 6) & 7;
            int ln = idx & 63;
            int q = ln >> 4, c = ln & 15;
            const float* wp = W + (t * 32 + q * 8) * DIM + n * 16 + c;
            half8 f;
#pragma unroll
            for (int j = 0; j < 8; ++j) f[j] = (_Float16)wp[j * DIM];
            outp[idx] = f;
        }
    } else {
        int k = (b - 3) * 256 + threadIdx.x;
        if (k < NG * DIM) pooled[k] = 0.f;
    }
}

// ---------------- pass1: LDS counting-sort each 4096-edge tile by bin ----------------
__launch_bounds__(256, 2)
__global__ void pass1_kernel(const int* __restrict__ src, const int* __restrict__ dst,
                             unsigned* __restrict__ chunks, int* __restrict__ lexg) {
    __shared__ unsigned sorted[CHSZ];
    __shared__ int h[256], lex[257], c2[256];
    int t = threadIdx.x;
    int c = blockIdx.x;
    int e0 = c * CHSZ;
    int nrec = NE - e0; if (nrec > CHSZ) nrec = CHSZ;
    h[t] = 0;
    __syncthreads();
    unsigned myrec[16];
#pragma unroll
    for (int j = 0; j < 16; ++j) {
        int i = t + j * 256;
        if (i < nrec) {
            int e = e0 + i;
            int d = __builtin_nontemporal_load(dst + e);
            int s = __builtin_nontemporal_load(src + e);
            myrec[j] = (unsigned)s | ((unsigned)(d & 255) << 16) | ((unsigned)(d >> 8) << 24);
            atomicAdd(&h[d >> 8], 1);
        } else myrec[j] = 0xFFFFFFFFu;
    }
    __syncthreads();
    if (t < 64) {               // wave-0 exclusive scan of h[0..255]
        int base = t * 4;
        int v0 = h[base], v1 = h[base + 1], v2 = h[base + 2], v3 = h[base + 3];
        int s = v0 + v1 + v2 + v3;
        int inc = s;
#pragma unroll
        for (int o = 1; o < 64; o <<= 1) {
            int u = __shfl_up(inc, o);
            if (t >= o) inc += u;
        }
        int pre = inc - s;
        lex[base] = pre;
        lex[base + 1] = pre + v0;
        lex[base + 2] = pre + v0 + v1;
        lex[base + 3] = pre + v0 + v1 + v2;
        if (t == 63) lex[256] = inc;
    }
    c2[t] = 0;
    __syncthreads();
#pragma unroll
    for (int j = 0; j < 16; ++j) {
        unsigned rec = myrec[j];
        if (rec != 0xFFFFFFFFu) {
            int bb = rec >> 24;
            int pos = lex[bb] + atomicAdd(&c2[bb], 1);
            sorted[pos] = rec;
        }
    }
    __syncthreads();
    for (int j = t; j < nrec; j += 256)
        __builtin_nontemporal_store(sorted[j], chunks + (size_t)c * CHSZ + j);
    if (t < 197) lexg[c * 197 + t] = lex[t];
}

// ---------------- pass2: per-bin gather + LDS sort by node; padded aligned CSR ----------
__launch_bounds__(256, 1)
__global__ void pass2_kernel(const unsigned* __restrict__ chunks, const int* __restrict__ lexg,
                             unsigned short* __restrict__ edges, int* __restrict__ rowbeg,
                             int* __restrict__ cntn, float* __restrict__ dq) {
    __shared__ unsigned short outb[BINCAP];   // 32 KB
    __shared__ unsigned recs[9472];           // 37 KB (cap: mean 8192, 14 sigma)
    __shared__ int rl[448], co[449];
    __shared__ int h[256], off[257], c2[256];
    int t = threadIdx.x;
    int b = blockIdx.x;   // 0..195
    for (int c = t; c < 448; c += 256)
        rl[c] = (c < NCH) ? (lexg[c * 197 + b + 1] - lexg[c * 197 + b]) : 0;
    __syncthreads();
    if (t < 64) {               // wave-0 exclusive scan of rl[0..447]
        int base = t * 7;
        int v[7], s = 0;
#pragma unroll
        for (int j = 0; j < 7; ++j) { v[j] = rl[base + j]; s += v[j]; }
        int inc = s;
#pragma unroll
        for (int o = 1; o < 64; o <<= 1) {
            int u = __shfl_up(inc, o);
            if (t >= o) inc += u;
        }
        int run = inc - s;
#pragma unroll
        for (int j = 0; j < 7; ++j) { co[base + j] = run; run += v[j]; }
        if (t == 63) co[448] = run;
    }
    h[t] = 0;
    __syncthreads();
    int n = co[448];
    for (int c = t; c < NCH; c += 256) {
        int s0 = lexg[c * 197 + b];
        int len = rl[c];
        int o = co[c];
        const unsigned* cp = chunks + (size_t)c * CHSZ + s0;
        for (int j = 0; j < len; ++j) recs[o + j] = cp[j];
    }
    __syncthreads();
    for (int i = t; i < n; i += 256) atomicAdd(&h[(recs[i] >> 16) & 255], 1);
    __syncthreads();
    if (t < 64) {               // wave-0 exclusive scan of ceil8(h)
        int base = t * 4;
        int v0 = (h[base] + 7) & ~7,     v1 = (h[base + 1] + 7) & ~7;
        int v2 = (h[base + 2] + 7) & ~7, v3 = (h[base + 3] + 7) & ~7;
        int s = v0 + v1 + v2 + v3;
        int inc = s;
#pragma unroll
        for (int o = 1; o < 64; o <<= 1) {
            int u = __shfl_up(inc, o);
            if (t >= o) inc += u;
        }
        int pre = inc - s;
        off[base] = pre;
        off[base + 1] = pre + v0;
        off[base + 2] = pre + v0 + v1;
        off[base + 3] = pre + v0 + v1 + v2;
        if (t == 63) off[256] = inc;
    }
    c2[t] = 0;
    __syncthreads();
    for (int i = t; i < n; i += 256) {
        unsigned rec = recs[i];
        int dl = (rec >> 16) & 255;
        int r = atomicAdd(&c2[dl], 1);
        outb[off[dl] + r] = (unsigned short)(rec & 0xFFFFu);
    }
    __syncthreads();
    int ptot = off[256];
    int B = b * BINCAP;
    for (int i = t; i < ptot; i += 256)
        edges[B + i] = outb[i];
    int node = b * 256 + t;
    if (node < NN) {
        rowbeg[node] = B + off[t];
        int d = h[t];
        cntn[node] = d;
        dq[node] = 1.0f / sqrtf((float)(d + 1));
    }
}

// ---------------- layer-0 GEMM: reads fp32 x directly, converts in-register ----------
__launch_bounds__(256, 2)
__global__ void gemm0_mfma(const float* __restrict__ x, const half8* __restrict__ wfl,
                           _Float16* __restrict__ hout) {
    __shared__ half8 Wf[2048];   // 32 KB
    int tid = threadIdx.x;
    for (int idx = tid; idx < 2048; idx += 256) Wf[idx] = wfl[idx];
    __syncthreads();
    int wid = tid >> 6, lane = tid & 63;
    int q = lane >> 4, m = lane & 15;
    int r0 = blockIdx.x * 64 + wid * 16;
    int arow = r0 + m;
    if (arow > NN - 1) arow = NN - 1;
    const vfloat4* ap = (const vfloat4*)(x + (size_t)arow * DIM + q * 8);
    half8 a0 = cvt8(ap[0],  ap[1]);
    half8 a1 = cvt8(ap[8],  ap[9]);
    half8 a2 = cvt8(ap[16], ap[17]);
    half8 a3 = cvt8(ap[24], ap[25]);
    floatx4 acc[8];
#pragma unroll
    for (int n = 0; n < 8; ++n) acc[n] = (floatx4){0.f, 0.f, 0.f, 0.f};
#pragma unroll
    for (int n = 0; n < 8; ++n)
        acc[n] = __builtin_amdgcn_mfma_f32_16x16x32_f16(a0, Wf[(0 * 8 + n) * 64 + lane], acc[n], 0, 0, 0);
#pragma unroll
    for (int n = 0; n < 8; ++n)
        acc[n] = __builtin_amdgcn_mfma_f32_16x16x32_f16(a1, Wf[(1 * 8 + n) * 64 + lane], acc[n], 0, 0, 0);
#pragma unroll
    for (int n = 0; n < 8; ++n)
        acc[n] = __builtin_amdgcn_mfma_f32_16x16x32_f16(a2, Wf[(2 * 8 + n) * 64 + lane], acc[n], 0, 0, 0);
#pragma unroll
    for (int n = 0; n < 8; ++n)
        acc[n] = __builtin_amdgcn_mfma_f32_16x16x32_f16(a3, Wf[(3 * 8 + n) * 64 + lane], acc[n], 0, 0, 0);
#pragma unroll
    for (int n = 0; n < 8; ++n) {
#pragma unroll
        for (int r = 0; r < 4; ++r) {
            int row = r0 + q * 4 + r;
            if (row < NN)
                hout[(size_t)row * DIM + n * 16 + m] = (_Float16)acc[n][r];
        }
    }
}

// ---------------- GEMM via MFMA: one 64-row group per block (fp16 input) ----------------
__launch_bounds__(256, 2)
__global__ void gemm_mfma(const _Float16* __restrict__ yin, const half8* __restrict__ wfl,
                          _Float16* __restrict__ hout) {
    __shared__ half8 Wf[2048];   // 32 KB
    int tid = threadIdx.x;
    for (int idx = tid; idx < 2048; idx += 256) Wf[idx] = wfl[idx];
    __syncthreads();
    int wid = tid >> 6, lane = tid & 63;
    int q = lane >> 4, m = lane & 15;
    int r0 = blockIdx.x * 64 + wid * 16;
    int arow = r0 + m;
    if (arow > NN - 1) arow = NN - 1;
    const half8* ap = (const half8*)(yin + (size_t)arow * DIM + q * 8);
    half8 a0 = ap[0], a1 = ap[4], a2 = ap[8], a3 = ap[12];
    floatx4 acc[8];
#pragma unroll
    for (int n = 0; n < 8; ++n) acc[n] = (floatx4){0.f, 0.f, 0.f, 0.f};
#pragma unroll
    for (int n = 0; n < 8; ++n)
        acc[n] = __builtin_amdgcn_mfma_f32_16x16x32_f16(a0, Wf[(0 * 8 + n) * 64 + lane], acc[n], 0, 0, 0);
#pragma unroll
    for (int n = 0; n < 8; ++n)
        acc[n] = __builtin_amdgcn_mfma_f32_16x16x32_f16(a1, Wf[(1 * 8 + n) * 64 + lane], acc[n], 0, 0, 0);
#pragma unroll
    for (int n = 0; n < 8; ++n)
        acc[n] = __builtin_amdgcn_mfma_f32_16x16x32_f16(a2, Wf[(2 * 8 + n) * 64 + lane], acc[n], 0, 0, 0);
#pragma unroll
    for (int n = 0; n < 8; ++n)
        acc[n] = __builtin_amdgcn_mfma_f32_16x16x32_f16(a3, Wf[(3 * 8 + n) * 64 + lane], acc[n], 0, 0, 0);
#pragma unroll
    for (int n = 0; n < 8; ++n) {
#pragma unroll
        for (int r = 0; r < 4; ++r) {
            int row = r0 + q * 4 + r;
            if (row < NN)
                hout[(size_t)row * DIM + n * 16 + m] = (_Float16)acc[n][r];
        }
    }
}

// ---------------- fused conv: 8-deep ALL-SCALAR gather (r11 body, no spill) ----------
__launch_bounds__(256, 8)
__global__ void conv_kernel(const half2v* __restrict__ h2, const float* __restrict__ bias,
                            const int* __restrict__ rowbeg, const int* __restrict__ cntn,
                            const unsigned short* __restrict__ edges, const float* __restrict__ dq,
                            half2v* __restrict__ out, const int* __restrict__ batch,
                            float* __restrict__ pooled, int do_pool) {
    int wid = threadIdx.x >> 6;
    int lane = threadIdx.x & 63;
    int node = blockIdx.x * 4 + wid;
    if (node >= NN) return;
    int deg = cntn[node];
    const unsigned short* ep = edges + rowbeg[node];   // 16B-aligned (8-slot padding)
    float ax = 0.f, ay = 0.f;
    int e = 0;
    for (; e + 8 <= deg; e += 8) {
        vuint4 pk = __builtin_nontemporal_load((const vuint4*)(ep + e));
        unsigned s0 = pk.x & 0xFFFFu, s1 = pk.x >> 16;
        unsigned s2 = pk.y & 0xFFFFu, s3 = pk.y >> 16;
        unsigned s4 = pk.z & 0xFFFFu, s5 = pk.z >> 16;
        unsigned s6 = pk.w & 0xFFFFu, s7 = pk.w >> 16;
        float d0 = dq[s0], d1 = dq[s1], d2 = dq[s2], d3 = dq[s3];
        float d4 = dq[s4], d5 = dq[s5], d6 = dq[s6], d7 = dq[s7];
        half2v v0 = h2[(size_t)s0 * 64 + lane];
        half2v v1 = h2[(size_t)s1 * 64 + lane];
        half2v v2 = h2[(size_t)s2 * 64 + lane];
        half2v v3 = h2[(size_t)s3 * 64 + lane];
        half2v v4 = h2[(size_t)s4 * 64 + lane];
        half2v v5 = h2[(size_t)s5 * 64 + lane];
        half2v v6 = h2[(size_t)s6 * 64 + lane];
        half2v v7 = h2[(size_t)s7 * 64 + lane];
        ax += d0 * (float)v0.x + d1 * (float)v1.x + d2 * (float)v2.x + d3 * (float)v3.x
            + d4 * (float)v4.x + d5 * (float)v5.x + d6 * (float)v6.x + d7 * (float)v7.x;
        ay += d0 * (float)v0.y + d1 * (float)v1.y + d2 * (float)v2.y + d3 * (float)v3.y
            + d4 * (float)v4.y + d5 * (float)v5.y + d6 * (float)v6.y + d7 * (float)v7.y;
    }
    for (; e < deg; ++e) {
        unsigned s = ep[e];
        float ds = dq[s];
        half2v v = h2[(size_t)s * 64 + lane];
        ax += ds * (float)v.x;
        ay += ds * (float)v.y;
    }
    float dqd = dq[node];
    float sn = dqd * dqd;      // selfn = 1/deg = dq^2
    half2v hvn = h2[(size_t)node * 64 + lane];
    ax = ax * dqd + sn * (float)hvn.x + bias[2 * lane];
    ay = ay * dqd + sn * (float)hvn.y + bias[2 * lane + 1];
    float ss = ax * ax + ay * ay;
#pragma unroll
    for (int off = 32; off; off >>= 1) ss += __shfl_xor(ss, off);
    float inv = 1.0f / fmaxf(sqrtf(ss), 1e-12f);
    float ox = fmaxf(ax * inv, 0.f);
    float oy = fmaxf(ay * inv, 0.f);
    if (!do_pool) {
        half2v o;
        o.x = (_Float16)ox;
        o.y = (_Float16)oy;
        out[(size_t)node * 64 + lane] = o;   // cached: y stays L2-hot for next GEMM
    } else {
        int g = batch[node];
        atomicAdd(&pooled[g * DIM + 2 * lane], ox);
        atomicAdd(&pooled[g * DIM + 2 * lane + 1], oy);
    }
}

// ---------------- head: z = relu(pooled@W1+b1); logits = z@W2+b2 ----------------
__launch_bounds__(128)
__global__ void head_kernel(const float* __restrict__ pooled, const float* __restrict__ w1,
                            const float* __restrict__ b1, const float* __restrict__ w2,
                            const float* __restrict__ b2, float* __restrict__ out) {
    __shared__ float sp[DIM];
    __shared__ float red[4];
    int g = blockIdx.x;
    int k = threadIdx.x;
    sp[k] = pooled[g * DIM + k];
    __syncthreads();
    float acc = b1[k];
#pragma unroll 8
    for (int j = 0; j < DIM; ++j) acc += sp[j] * w1[j * DIM + k];
    float z = fmaxf(acc, 0.f);
    float p0 = z * w2[k * 2 + 0];
    float p1 = z * w2[k * 2 + 1];
#pragma unroll
    for (int off = 32; off; off >>= 1) {
        p0 += __shfl_xor(p0, off);
        p1 += __shfl_xor(p1, off);
    }
    if ((k & 63) == 0) {
        red[(k >> 6) * 2 + 0] = p0;
        red[(k >> 6) * 2 + 1] = p1;
    }
    __syncthreads();
    if (k == 0) {
        out[g * 2 + 0] = red[0] + red[2] + b2[0];
        out[g * 2 + 1] = red[1] + red[3] + b2[1];
    }
}

extern "C" void kernel_launch(void* const* d_in, const int* in_sizes, int n_in,
                              void* d_out, int out_size, void* d_ws, size_t ws_size,
                              hipStream_t stream) {
    const float* x    = (const float*)d_in[0];
    const int* eidx   = (const int*)d_in[1];
    const int* batch  = (const int*)d_in[2];
    const float* W0   = (const float*)d_in[3];
    const float* b0   = (const float*)d_in[4];
    const float* W1   = (const float*)d_in[5];
    const float* b1   = (const float*)d_in[6];
    const float* W2   = (const float*)d_in[7];
    const float* b2   = (const float*)d_in[8];
    const float* l1w  = (const float*)d_in[9];
    const float* l1b  = (const float*)d_in[10];
    const float* l2w  = (const float*)d_in[11];
    const float* l2b  = (const float*)d_in[12];
    float* out = (float*)d_out;

    #define ALIGN256(v) (((size_t)(v) + 255) & ~(size_t)255)
    char* w = (char*)d_ws;
    float* dq     = (float*)w; w += ALIGN256((size_t)NN * 4);
    int*   rowbeg = (int*)w;   w += ALIGN256((size_t)NN * 4);
    int*   cntn   = (int*)w;   w += ALIGN256((size_t)NN * 4);
    int*   lexg   = (int*)w;   w += ALIGN256((size_t)NCH * 197 * 4);
    unsigned* chunks = (unsigned*)w; w += ALIGN256((size_t)NCH * CHSZ * 4);
    unsigned short* edges = (unsigned short*)w; w += ALIGN256((size_t)NBINS * BINCAP * 2);
    half8* wf     = (half8*)w; w += ALIGN256((size_t)3 * 2048 * 16);
    _Float16* bufh = (_Float16*)w; w += ALIGN256((size_t)NN * DIM * 2);
    _Float16* bufy = (_Float16*)w; w += ALIGN256((size_t)NN * DIM * 2);
    float* pooled = (float*)w; w += ALIGN256((size_t)NG * DIM * 4);

    const int* src = eidx;
    const int* dst = eidx + NE;

    initcvt_kernel<<<3 + (NG * DIM + 255) / 256, 256, 0, stream>>>(W0, W1, W2, wf, pooled);
    pass1_kernel<<<NCH, 256, 0, stream>>>(src, dst, chunks, lexg);
    pass2_kernel<<<NBINS, 256, 0, stream>>>(chunks, lexg, edges, rowbeg, cntn, dq);

    const int CG = (NN + 3) / 4;        // 12500 blocks, one wave per node
    const int GG = (NN + 63) / 64;      // 782 blocks, one 64-row group per block

    gemm0_mfma<<<GG, 256, 0, stream>>>(x, wf, bufh);
    conv_kernel<<<CG, 256, 0, stream>>>((const half2v*)bufh, b0, rowbeg, cntn, edges, dq,
                                        (half2v*)bufy, batch, pooled, 0);
    gemm_mfma<<<GG, 256, 0, stream>>>(bufy, wf + 2048, bufh);
    conv_kernel<<<CG, 256, 0, stream>>>((const half2v*)bufh, b1, rowbeg, cntn, edges, dq,
                                        (half2v*)bufy, batch, pooled, 0);
    gemm_mfma<<<GG, 256, 0, stream>>>(bufy, wf + 4096, bufh);
    conv_kernel<<<CG, 256, 0, stream>>>((const half2v*)bufh, b2, rowbeg, cntn, edges, dq,
                                        (half2v*)bufy, batch, pooled, 1);
    head_kernel<<<NG, 128, 0, stream>>>(pooled, l1w, l1b, l2w, l2b, out);
}